// Round 1
// baseline (2313.711 us; speedup 1.0000x reference)
//
#include <hip/hip_runtime.h>

#define N_NODES 50000
#define N_EDGES 800000
#define IN_CH   128
#define HID     128
#define OUT_CH  64

// ---------------- degree / norm precompute ----------------

__global__ void k_init_deg(float* __restrict__ deg) {
    int i = blockIdx.x * blockDim.x + threadIdx.x;
    if (i < N_NODES) deg[i] = 1.0f;   // self-loop
}

__global__ void k_count(const int* __restrict__ dst, float* __restrict__ deg) {
    int i = blockIdx.x * blockDim.x + threadIdx.x;
    if (i < N_EDGES) atomicAdd(&deg[dst[i]], 1.0f);
}

__global__ void k_dis(const float* __restrict__ deg, float* __restrict__ dis) {
    int i = blockIdx.x * blockDim.x + threadIdx.x;
    if (i < N_NODES) dis[i] = rsqrtf(deg[i]);   // deg >= 1 always (self-loop)
}

__global__ void k_norm(const int* __restrict__ src, const int* __restrict__ dst,
                       const float* __restrict__ dis, float* __restrict__ norm) {
    int i = blockIdx.x * blockDim.x + threadIdx.x;
    if (i < N_EDGES) norm[i] = dis[src[i]] * dis[dst[i]];
}

// ---------------- GEMM1: h1 = x @ W1  [50000,128]x[128,128] ----------------

#define G1_ROWS 32
__global__ __launch_bounds__(256) void k_gemm1(const float* __restrict__ x,
                                               const float* __restrict__ W,
                                               float* __restrict__ h) {
    __shared__ float Ws[IN_CH * HID];        // 64 KB
    __shared__ float xs[G1_ROWS * IN_CH];    // 16 KB
    const int t = threadIdx.x;
    const int row0 = blockIdx.x * G1_ROWS;

    for (int i = t; i < IN_CH * HID; i += 256) Ws[i] = W[i];
    for (int i = t; i < G1_ROWS * IN_CH; i += 256) {
        int r = row0 + (i >> 7);
        xs[i] = (r < N_NODES) ? x[(long)row0 * IN_CH + i] : 0.0f;
    }
    __syncthreads();

    for (int idx = t; idx < G1_ROWS * HID; idx += 256) {
        int r = idx >> 7, c = idx & (HID - 1);
        if (row0 + r >= N_NODES) continue;
        const float* xr = &xs[r * IN_CH];
        float acc = 0.0f;
#pragma unroll 8
        for (int k = 0; k < IN_CH; ++k) acc += xr[k] * Ws[k * HID + c];
        h[(long)(row0 + r) * HID + c] = acc;
    }
}

// ---------------- layer-1 self-loop init: agg = h*dis^2 + b1 ----------------

__global__ void k_self1(const float* __restrict__ h, const float* __restrict__ dis,
                        const float* __restrict__ b1, float* __restrict__ agg) {
    int i = blockIdx.x * blockDim.x + threadIdx.x;
    if (i < N_NODES * HID) {
        int r = i >> 7, c = i & (HID - 1);
        float d = dis[r];
        agg[i] = h[i] * d * d + b1[c];
    }
}

// ---------------- layer-1 edge scatter ----------------

__global__ void k_scatter1(const int* __restrict__ src, const int* __restrict__ dst,
                           const float* __restrict__ norm, const float* __restrict__ h,
                           float* __restrict__ agg) {
    long gid = (long)blockIdx.x * blockDim.x + threadIdx.x;
    if (gid >= (long)N_EDGES * (HID / 4)) return;
    int e = (int)(gid >> 5);          // HID/4 = 32 groups
    int g = ((int)gid & 31) << 2;
    int s = src[e], d = dst[e];
    float n = norm[e];
    const float4 v = *(const float4*)&h[(long)s * HID + g];
    float* out = &agg[(long)d * HID + g];
    atomicAdd(out + 0, v.x * n);
    atomicAdd(out + 1, v.y * n);
    atomicAdd(out + 2, v.z * n);
    atomicAdd(out + 3, v.w * n);
}

// ---------------- GEMM2: h3 = relu(agg1) @ W2  [50000,128]x[128,64] ----------------

#define G2_ROWS 32
__global__ __launch_bounds__(256) void k_gemm2(const float* __restrict__ agg,
                                               const float* __restrict__ W,
                                               float* __restrict__ h) {
    __shared__ float Ws[HID * OUT_CH];       // 32 KB
    __shared__ float xs[G2_ROWS * HID];      // 16 KB
    const int t = threadIdx.x;
    const int row0 = blockIdx.x * G2_ROWS;

    for (int i = t; i < HID * OUT_CH; i += 256) Ws[i] = W[i];
    for (int i = t; i < G2_ROWS * HID; i += 256) {
        int r = row0 + (i >> 7);
        xs[i] = (r < N_NODES) ? fmaxf(agg[(long)row0 * HID + i], 0.0f) : 0.0f;
    }
    __syncthreads();

    for (int idx = t; idx < G2_ROWS * OUT_CH; idx += 256) {
        int r = idx / OUT_CH, c = idx % OUT_CH;
        if (row0 + r >= N_NODES) continue;
        const float* xr = &xs[r * HID];
        float acc = 0.0f;
#pragma unroll 8
        for (int k = 0; k < HID; ++k) acc += xr[k] * Ws[k * OUT_CH + c];
        h[(long)(row0 + r) * OUT_CH + c] = acc;
    }
}

// ---------------- layer-2 self-loop init + bias: out = h3*dis^2 + b2 ----------------

__global__ void k_self2(const float* __restrict__ h, const float* __restrict__ dis,
                        const float* __restrict__ b2, float* __restrict__ out) {
    int i = blockIdx.x * blockDim.x + threadIdx.x;
    if (i < N_NODES * OUT_CH) {
        int r = i / OUT_CH, c = i % OUT_CH;
        float d = dis[r];
        out[i] = h[i] * d * d + b2[c];
    }
}

// ---------------- layer-2 edge scatter ----------------

__global__ void k_scatter2(const int* __restrict__ src, const int* __restrict__ dst,
                           const float* __restrict__ norm, const float* __restrict__ h,
                           float* __restrict__ out) {
    long gid = (long)blockIdx.x * blockDim.x + threadIdx.x;
    if (gid >= (long)N_EDGES * (OUT_CH / 4)) return;
    int e = (int)(gid >> 4);          // OUT_CH/4 = 16 groups
    int g = ((int)gid & 15) << 2;
    int s = src[e], d = dst[e];
    float n = norm[e];
    const float4 v = *(const float4*)&h[(long)s * OUT_CH + g];
    float* o = &out[(long)d * OUT_CH + g];
    atomicAdd(o + 0, v.x * n);
    atomicAdd(o + 1, v.y * n);
    atomicAdd(o + 2, v.z * n);
    atomicAdd(o + 3, v.w * n);
}

// ---------------- launch ----------------

extern "C" void kernel_launch(void* const* d_in, const int* in_sizes, int n_in,
                              void* d_out, int out_size, void* d_ws, size_t ws_size,
                              hipStream_t stream) {
    const float* x   = (const float*)d_in[0];
    const int*   ei  = (const int*)d_in[1];     // [2, E] int32
    const float* W1  = (const float*)d_in[2];
    const float* b1  = (const float*)d_in[3];
    const float* W2  = (const float*)d_in[4];
    const float* b2  = (const float*)d_in[5];
    float* out = (float*)d_out;

    const int* src = ei;
    const int* dst = ei + N_EDGES;

    // workspace layout (floats)
    float* ws   = (float*)d_ws;
    float* deg  = ws;                       // N
    float* dis  = deg  + N_NODES;           // N
    float* norm = dis  + N_NODES;           // E
    float* h1   = norm + N_EDGES;           // N*128
    float* agg1 = h1   + (long)N_NODES * HID;     // N*128
    float* h3   = agg1 + (long)N_NODES * HID;     // N*64

    const int B = 256;

    k_init_deg<<<(N_NODES + B - 1) / B, B, 0, stream>>>(deg);
    k_count<<<(N_EDGES + B - 1) / B, B, 0, stream>>>(dst, deg);
    k_dis<<<(N_NODES + B - 1) / B, B, 0, stream>>>(deg, dis);
    k_norm<<<(N_EDGES + B - 1) / B, B, 0, stream>>>(src, dst, dis, norm);

    k_gemm1<<<(N_NODES + G1_ROWS - 1) / G1_ROWS, B, 0, stream>>>(x, W1, h1);
    k_self1<<<(N_NODES * HID + B - 1) / B, B, 0, stream>>>(h1, dis, b1, agg1);
    k_scatter1<<<(int)(((long)N_EDGES * (HID / 4) + B - 1) / B), B, 0, stream>>>(
        src, dst, norm, h1, agg1);

    k_gemm2<<<(N_NODES + G2_ROWS - 1) / G2_ROWS, B, 0, stream>>>(agg1, W2, h3);
    k_self2<<<(N_NODES * OUT_CH + B - 1) / B, B, 0, stream>>>(h3, dis, b2, out);
    k_scatter2<<<(int)(((long)N_EDGES * (OUT_CH / 4) + B - 1) / B), B, 0, stream>>>(
        src, dst, norm, h3, out);
}

// Round 2
// 582.227 us; speedup vs baseline: 3.9739x; 3.9739x over previous
//
#include <hip/hip_runtime.h>

#define N_NODES 50000
#define N_EDGES 800000
#define IN_CH   128
#define HID     128
#define OUT_CH  64

// ================= CSR build =================

__global__ void k_zero(int* __restrict__ cnt) {
    int i = blockIdx.x * blockDim.x + threadIdx.x;
    if (i < N_NODES) cnt[i] = 0;
}

__global__ void k_hist(const int* __restrict__ dst, int* __restrict__ cnt) {
    int i = blockIdx.x * blockDim.x + threadIdx.x;
    if (i < N_EDGES) atomicAdd(&cnt[dst[i]], 1);
}

// single-block exclusive scan: cnt -> row_ptr; cnt becomes cursor (= row start)
__global__ __launch_bounds__(1024) void k_scan(int* __restrict__ cnt, int* __restrict__ row_ptr) {
    __shared__ int smem[1024];
    __shared__ int running;
    if (threadIdx.x == 0) running = 0;
    __syncthreads();
    for (int base = 0; base < N_NODES; base += 1024) {
        int i = base + threadIdx.x;
        int v = (i < N_NODES) ? cnt[i] : 0;
        smem[threadIdx.x] = v;
        __syncthreads();
        for (int off = 1; off < 1024; off <<= 1) {
            int t = (threadIdx.x >= off) ? smem[threadIdx.x - off] : 0;
            __syncthreads();
            smem[threadIdx.x] += t;
            __syncthreads();
        }
        int incl = smem[threadIdx.x];
        int chunk_total = smem[1023];
        int rp = running + (incl - v);
        if (i < N_NODES) { row_ptr[i] = rp; cnt[i] = rp; }   // cnt reused as cursor
        __syncthreads();
        if (threadIdx.x == 0) running += chunk_total;
        __syncthreads();
    }
    if (threadIdx.x == 0) row_ptr[N_NODES] = N_EDGES;
}

__global__ void k_dis(const int* __restrict__ row_ptr, float* __restrict__ dis) {
    int i = blockIdx.x * blockDim.x + threadIdx.x;
    if (i < N_NODES)
        dis[i] = rsqrtf((float)(row_ptr[i + 1] - row_ptr[i]) + 1.0f);  // +1 self-loop
}

__global__ void k_fill(const int* __restrict__ src, const int* __restrict__ dst,
                       int* __restrict__ cursor, int* __restrict__ col) {
    int e = blockIdx.x * blockDim.x + threadIdx.x;
    if (e < N_EDGES) {
        int pos = atomicAdd(&cursor[dst[e]], 1);
        col[pos] = src[e];
    }
}

// ================= GEMM1: g1 = (x @ W1) * dis[row] =================

#define G1_ROWS 32
__global__ __launch_bounds__(256) void k_gemm1(const float* __restrict__ x,
                                               const float* __restrict__ W,
                                               const float* __restrict__ dis,
                                               float* __restrict__ g) {
    __shared__ float Ws[IN_CH * HID];        // 64 KB
    __shared__ float xs[G1_ROWS * IN_CH];    // 16 KB
    const int t = threadIdx.x;
    const int row0 = blockIdx.x * G1_ROWS;

    for (int i = t; i < IN_CH * HID; i += 256) Ws[i] = W[i];
    for (int i = t; i < G1_ROWS * IN_CH; i += 256) {
        int r = row0 + (i >> 7);
        xs[i] = (r < N_NODES) ? x[(long)row0 * IN_CH + i] : 0.0f;
    }
    __syncthreads();

    for (int idx = t; idx < G1_ROWS * HID; idx += 256) {
        int r = idx >> 7, c = idx & (HID - 1);
        if (row0 + r >= N_NODES) continue;
        const float* xr = &xs[r * IN_CH];
        float acc = 0.0f;
#pragma unroll 8
        for (int k = 0; k < IN_CH; ++k) acc += xr[k] * Ws[k * HID + c];
        g[(long)(row0 + r) * HID + c] = acc * dis[row0 + r];
    }
}

// ================= layer-1 aggregate: a1 = relu(dis[r]*(g1[r] + sum g1[src]) + b1) =====

__global__ __launch_bounds__(256) void k_agg1(const int* __restrict__ row_ptr,
                                              const int* __restrict__ col,
                                              const float* __restrict__ dis,
                                              const float* __restrict__ g1,
                                              const float* __restrict__ b1,
                                              float* __restrict__ a1) {
    int r = blockIdx.x * 4 + (threadIdx.x >> 6);
    if (r >= N_NODES) return;
    int lane = threadIdx.x & 63;
    int c = lane << 1;
    int beg = row_ptr[r], end = row_ptr[r + 1];

    float2 acc = *(const float2*)&g1[(long)r * HID + c];   // self-loop term
    for (int e = beg; e < end; ++e) {
        int s = col[e];
        float2 v = *(const float2*)&g1[(long)s * HID + c];
        acc.x += v.x; acc.y += v.y;
    }
    float d = dis[r];
    float2 o;
    o.x = fmaxf(acc.x * d + b1[c], 0.0f);
    o.y = fmaxf(acc.y * d + b1[c + 1], 0.0f);
    *(float2*)&a1[(long)r * HID + c] = o;
}

// ================= GEMM2: g3 = (a1 @ W2) * dis[row] =================

#define G2_ROWS 32
__global__ __launch_bounds__(256) void k_gemm2(const float* __restrict__ a1,
                                               const float* __restrict__ W,
                                               const float* __restrict__ dis,
                                               float* __restrict__ g) {
    __shared__ float Ws[HID * OUT_CH];       // 32 KB
    __shared__ float xs[G2_ROWS * HID];      // 16 KB
    const int t = threadIdx.x;
    const int row0 = blockIdx.x * G2_ROWS;

    for (int i = t; i < HID * OUT_CH; i += 256) Ws[i] = W[i];
    for (int i = t; i < G2_ROWS * HID; i += 256) {
        int r = row0 + (i >> 7);
        xs[i] = (r < N_NODES) ? a1[(long)row0 * HID + i] : 0.0f;
    }
    __syncthreads();

    for (int idx = t; idx < G2_ROWS * OUT_CH; idx += 256) {
        int r = idx / OUT_CH, c = idx % OUT_CH;
        if (row0 + r >= N_NODES) continue;
        const float* xr = &xs[r * HID];
        float acc = 0.0f;
#pragma unroll 8
        for (int k = 0; k < HID; ++k) acc += xr[k] * Ws[k * OUT_CH + c];
        g[(long)(row0 + r) * OUT_CH + c] = acc * dis[row0 + r];
    }
}

// ================= layer-2 aggregate: out = dis[r]*(g3[r] + sum g3[src]) + b2 =====

__global__ __launch_bounds__(256) void k_agg2(const int* __restrict__ row_ptr,
                                              const int* __restrict__ col,
                                              const float* __restrict__ dis,
                                              const float* __restrict__ g3,
                                              const float* __restrict__ b2,
                                              float* __restrict__ out) {
    int r = blockIdx.x * 4 + (threadIdx.x >> 6);
    if (r >= N_NODES) return;
    int lane = threadIdx.x & 63;   // channel
    int beg = row_ptr[r], end = row_ptr[r + 1];

    float acc = g3[(long)r * OUT_CH + lane];               // self-loop term
    for (int e = beg; e < end; ++e) {
        int s = col[e];
        acc += g3[(long)s * OUT_CH + lane];
    }
    out[(long)r * OUT_CH + lane] = acc * dis[r] + b2[lane];
}

// ================= launch =================

extern "C" void kernel_launch(void* const* d_in, const int* in_sizes, int n_in,
                              void* d_out, int out_size, void* d_ws, size_t ws_size,
                              hipStream_t stream) {
    const float* x   = (const float*)d_in[0];
    const int*   ei  = (const int*)d_in[1];     // [2, E] int32
    const float* W1  = (const float*)d_in[2];
    const float* b1  = (const float*)d_in[3];
    const float* W2  = (const float*)d_in[4];
    const float* b2  = (const float*)d_in[5];
    float* out = (float*)d_out;

    const int* src = ei;
    const int* dst = ei + N_EDGES;

    // ---- workspace layout ----
    char* p = (char*)d_ws;
    int* cnt     = (int*)p;              p += 50048 * 4;          // histogram -> cursor
    int* row_ptr = (int*)p;              p += 50064 * 4;          // N+1, padded
    int* col     = (int*)p;              p += 800000 * 4;         // dst-sorted src ids
    float* dis   = (float*)p;            p += 50048 * 4;
    float* g1    = (float*)p;            p += (long)N_NODES * HID * 4;
    float* a1    = (float*)p;            p += (long)N_NODES * HID * 4;
    float* g3    = (float*)p;            // N*64

    const int B = 256;

    k_zero<<<(N_NODES + B - 1) / B, B, 0, stream>>>(cnt);
    k_hist<<<(N_EDGES + B - 1) / B, B, 0, stream>>>(dst, cnt);
    k_scan<<<1, 1024, 0, stream>>>(cnt, row_ptr);
    k_dis<<<(N_NODES + B - 1) / B, B, 0, stream>>>(row_ptr, dis);
    k_fill<<<(N_EDGES + B - 1) / B, B, 0, stream>>>(src, dst, cnt, col);

    k_gemm1<<<(N_NODES + G1_ROWS - 1) / G1_ROWS, B, 0, stream>>>(x, W1, dis, g1);
    k_agg1<<<(N_NODES + 3) / 4, B, 0, stream>>>(row_ptr, col, dis, g1, b1, a1);
    k_gemm2<<<(N_NODES + G2_ROWS - 1) / G2_ROWS, B, 0, stream>>>(a1, W2, dis, g3);
    k_agg2<<<(N_NODES + 3) / 4, B, 0, stream>>>(row_ptr, col, dis, g3, b2, out);
}

// Round 3
// 407.048 us; speedup vs baseline: 5.6841x; 1.4304x over previous
//
#include <hip/hip_runtime.h>

#define N_NODES 50000
#define N_EDGES 800000
#define IN_CH   128
#define HID     128
#define OUT_CH  64

// ================= CSR build =================

__global__ void k_zero(int* __restrict__ cnt) {
    int i = blockIdx.x * blockDim.x + threadIdx.x;
    if (i < N_NODES) cnt[i] = 0;
}

__global__ void k_hist(const int* __restrict__ dst, int* __restrict__ cnt) {
    int i = blockIdx.x * blockDim.x + threadIdx.x;
    if (i < N_EDGES) atomicAdd(&cnt[dst[i]], 1);
}

// single-block exclusive scan: cnt -> row_ptr; cnt becomes cursor (= row start)
__global__ __launch_bounds__(1024) void k_scan(int* __restrict__ cnt, int* __restrict__ row_ptr) {
    __shared__ int smem[1024];
    __shared__ int running;
    if (threadIdx.x == 0) running = 0;
    __syncthreads();
    for (int base = 0; base < N_NODES; base += 1024) {
        int i = base + threadIdx.x;
        int v = (i < N_NODES) ? cnt[i] : 0;
        smem[threadIdx.x] = v;
        __syncthreads();
        for (int off = 1; off < 1024; off <<= 1) {
            int t = (threadIdx.x >= off) ? smem[threadIdx.x - off] : 0;
            __syncthreads();
            smem[threadIdx.x] += t;
            __syncthreads();
        }
        int incl = smem[threadIdx.x];
        int chunk_total = smem[1023];
        int rp = running + (incl - v);
        if (i < N_NODES) { row_ptr[i] = rp; cnt[i] = rp; }
        __syncthreads();
        if (threadIdx.x == 0) running += chunk_total;
        __syncthreads();
    }
    if (threadIdx.x == 0) row_ptr[N_NODES] = N_EDGES;
}

__global__ void k_dis(const int* __restrict__ row_ptr, float* __restrict__ dis) {
    int i = blockIdx.x * blockDim.x + threadIdx.x;
    if (i < N_NODES)
        dis[i] = rsqrtf((float)(row_ptr[i + 1] - row_ptr[i]) + 1.0f);
}

__global__ void k_fill(const int* __restrict__ src, const int* __restrict__ dst,
                       int* __restrict__ cursor, int* __restrict__ col) {
    int e = blockIdx.x * blockDim.x + threadIdx.x;
    if (e < N_EDGES) {
        int pos = atomicAdd(&cursor[dst[e]], 1);
        col[pos] = src[e];
    }
}

// ================= register-tiled GEMM1: g1 = (x @ W1) * dis[row] =================
// 64 rows x 64 cols per block; 256 threads, 4x4 micro-tile each.

__global__ __launch_bounds__(256, 2) void k_gemm1(const float* __restrict__ x,
                                                  const float* __restrict__ W,
                                                  const float* __restrict__ dis,
                                                  float* __restrict__ g) {
    __shared__ float xs[64][132];     // padded: conflict-free row reads
    __shared__ float Ws[128][64];
    const int row0 = blockIdx.x * 64;
    const int c0   = blockIdx.y * 64;
    const int tid  = threadIdx.x;

    // stage x tile: 64 rows x 32 float4
    for (int i = tid; i < 64 * 32; i += 256) {
        int r = i >> 5, k4 = (i & 31) << 2;
        int gr = row0 + r;
        float4 v = make_float4(0.f, 0.f, 0.f, 0.f);
        if (gr < N_NODES) v = *(const float4*)&x[(long)gr * IN_CH + k4];
        *(float4*)&xs[r][k4] = v;
    }
    // stage W cols [c0, c0+64): 128 rows x 16 float4
    for (int i = tid; i < 128 * 16; i += 256) {
        int k = i >> 4, c4 = (i & 15) << 2;
        *(float4*)&Ws[k][c4] = *(const float4*)&W[k * HID + c0 + c4];
    }
    __syncthreads();

    const int tr = tid >> 4, tc = tid & 15;
    const int r0 = tr << 2, cc0 = tc << 2;

    float acc[16] = {};
    for (int k = 0; k < 128; k += 4) {
        float4 A[4], B[4];
#pragma unroll
        for (int i = 0; i < 4; ++i) A[i] = *(const float4*)&xs[r0 + i][k];
#pragma unroll
        for (int kk = 0; kk < 4; ++kk) B[kk] = *(const float4*)&Ws[k + kk][cc0];
        const float* a = (const float*)A;
        const float* b = (const float*)B;
#pragma unroll
        for (int i = 0; i < 4; ++i)
#pragma unroll
            for (int j = 0; j < 4; ++j)
#pragma unroll
                for (int kk = 0; kk < 4; ++kk)
                    acc[i * 4 + j] = fmaf(a[i * 4 + kk], b[kk * 4 + j], acc[i * 4 + j]);
    }

#pragma unroll
    for (int i = 0; i < 4; ++i) {
        int gr = row0 + r0 + i;
        if (gr < N_NODES) {
            float d = dis[gr];
            float4 o = make_float4(acc[i * 4 + 0] * d, acc[i * 4 + 1] * d,
                                   acc[i * 4 + 2] * d, acc[i * 4 + 3] * d);
            *(float4*)&g[(long)gr * HID + c0 + cc0] = o;
        }
    }
}

// ================= register-tiled GEMM2: g3 = (a1 @ W2) * dis[row] =================

__global__ __launch_bounds__(256, 2) void k_gemm2(const float* __restrict__ a1,
                                                  const float* __restrict__ W,
                                                  const float* __restrict__ dis,
                                                  float* __restrict__ g) {
    __shared__ float xs[64][132];
    __shared__ float Ws[128][64];
    const int row0 = blockIdx.x * 64;
    const int tid  = threadIdx.x;

    for (int i = tid; i < 64 * 32; i += 256) {
        int r = i >> 5, k4 = (i & 31) << 2;
        int gr = row0 + r;
        float4 v = make_float4(0.f, 0.f, 0.f, 0.f);
        if (gr < N_NODES) v = *(const float4*)&a1[(long)gr * HID + k4];
        *(float4*)&xs[r][k4] = v;
    }
    for (int i = tid; i < 128 * 16; i += 256) {
        int k = i >> 4, c4 = (i & 15) << 2;
        *(float4*)&Ws[k][c4] = *(const float4*)&W[k * OUT_CH + c4];
    }
    __syncthreads();

    const int tr = tid >> 4, tc = tid & 15;
    const int r0 = tr << 2, cc0 = tc << 2;

    float acc[16] = {};
    for (int k = 0; k < 128; k += 4) {
        float4 A[4], B[4];
#pragma unroll
        for (int i = 0; i < 4; ++i) A[i] = *(const float4*)&xs[r0 + i][k];
#pragma unroll
        for (int kk = 0; kk < 4; ++kk) B[kk] = *(const float4*)&Ws[k + kk][cc0];
        const float* a = (const float*)A;
        const float* b = (const float*)B;
#pragma unroll
        for (int i = 0; i < 4; ++i)
#pragma unroll
            for (int j = 0; j < 4; ++j)
#pragma unroll
                for (int kk = 0; kk < 4; ++kk)
                    acc[i * 4 + j] = fmaf(a[i * 4 + kk], b[kk * 4 + j], acc[i * 4 + j]);
    }

#pragma unroll
    for (int i = 0; i < 4; ++i) {
        int gr = row0 + r0 + i;
        if (gr < N_NODES) {
            float d = dis[gr];
            float4 o = make_float4(acc[i * 4 + 0] * d, acc[i * 4 + 1] * d,
                                   acc[i * 4 + 2] * d, acc[i * 4 + 3] * d);
            *(float4*)&g[(long)gr * OUT_CH + cc0] = o;
        }
    }
}

// ===== layer-1 aggregate: a1 = relu(dis[r]*(g1[r] + sum g1[src]) + b1) =====
// one wave per row; lanes 0-31 even edges, 32-63 odd edges; float4 per lane.

__global__ __launch_bounds__(256) void k_agg1(const int* __restrict__ row_ptr,
                                              const int* __restrict__ col,
                                              const float* __restrict__ dis,
                                              const float* __restrict__ g1,
                                              const float* __restrict__ b1,
                                              float* __restrict__ a1) {
    int r = blockIdx.x * 4 + (threadIdx.x >> 6);
    if (r >= N_NODES) return;
    const int lane = threadIdx.x & 63;
    const int half = lane >> 5;
    const int cl = (lane & 31) << 2;
    const int beg = row_ptr[r], end = row_ptr[r + 1];

    float4 acc0 = make_float4(0.f, 0.f, 0.f, 0.f);
    float4 acc1 = make_float4(0.f, 0.f, 0.f, 0.f);
    int e = beg + half;
    for (; e + 2 < end; e += 4) {
        int s0 = col[e], s1 = col[e + 2];
        const float4 v0 = *(const float4*)&g1[(long)s0 * HID + cl];
        const float4 v1 = *(const float4*)&g1[(long)s1 * HID + cl];
        acc0.x += v0.x; acc0.y += v0.y; acc0.z += v0.z; acc0.w += v0.w;
        acc1.x += v1.x; acc1.y += v1.y; acc1.z += v1.z; acc1.w += v1.w;
    }
    if (e < end) {
        int s = col[e];
        const float4 v = *(const float4*)&g1[(long)s * HID + cl];
        acc0.x += v.x; acc0.y += v.y; acc0.z += v.z; acc0.w += v.w;
    }
    acc0.x += acc1.x; acc0.y += acc1.y; acc0.z += acc1.z; acc0.w += acc1.w;

    acc0.x += __shfl_down(acc0.x, 32);
    acc0.y += __shfl_down(acc0.y, 32);
    acc0.z += __shfl_down(acc0.z, 32);
    acc0.w += __shfl_down(acc0.w, 32);

    if (half == 0) {
        const float4 self = *(const float4*)&g1[(long)r * HID + cl];
        const float d = dis[r];
        float4 o;
        o.x = fmaxf((acc0.x + self.x) * d + b1[cl + 0], 0.f);
        o.y = fmaxf((acc0.y + self.y) * d + b1[cl + 1], 0.f);
        o.z = fmaxf((acc0.z + self.z) * d + b1[cl + 2], 0.f);
        o.w = fmaxf((acc0.w + self.w) * d + b1[cl + 3], 0.f);
        *(float4*)&a1[(long)r * HID + cl] = o;
    }
}

// ===== layer-2 aggregate: out = dis[r]*(g3[r] + sum g3[src]) + b2 =====
// one wave per row; lane quarters over edges; float4 per lane (16 lanes cover 64 ch).

__global__ __launch_bounds__(256) void k_agg2(const int* __restrict__ row_ptr,
                                              const int* __restrict__ col,
                                              const float* __restrict__ dis,
                                              const float* __restrict__ g3,
                                              const float* __restrict__ b2,
                                              float* __restrict__ out) {
    int r = blockIdx.x * 4 + (threadIdx.x >> 6);
    if (r >= N_NODES) return;
    const int lane = threadIdx.x & 63;
    const int q = lane >> 4;
    const int cl = (lane & 15) << 2;
    const int beg = row_ptr[r], end = row_ptr[r + 1];

    float4 acc0 = make_float4(0.f, 0.f, 0.f, 0.f);
    float4 acc1 = make_float4(0.f, 0.f, 0.f, 0.f);
    int e = beg + q;
    for (; e + 4 < end; e += 8) {
        int s0 = col[e], s1 = col[e + 4];
        const float4 v0 = *(const float4*)&g3[(long)s0 * OUT_CH + cl];
        const float4 v1 = *(const float4*)&g3[(long)s1 * OUT_CH + cl];
        acc0.x += v0.x; acc0.y += v0.y; acc0.z += v0.z; acc0.w += v0.w;
        acc1.x += v1.x; acc1.y += v1.y; acc1.z += v1.z; acc1.w += v1.w;
    }
    if (e < end) {
        int s = col[e];
        const float4 v = *(const float4*)&g3[(long)s * OUT_CH + cl];
        acc0.x += v.x; acc0.y += v.y; acc0.z += v.z; acc0.w += v.w;
    }
    acc0.x += acc1.x; acc0.y += acc1.y; acc0.z += acc1.z; acc0.w += acc1.w;

    acc0.x += __shfl_down(acc0.x, 32);
    acc0.y += __shfl_down(acc0.y, 32);
    acc0.z += __shfl_down(acc0.z, 32);
    acc0.w += __shfl_down(acc0.w, 32);
    acc0.x += __shfl_down(acc0.x, 16);
    acc0.y += __shfl_down(acc0.y, 16);
    acc0.z += __shfl_down(acc0.z, 16);
    acc0.w += __shfl_down(acc0.w, 16);

    if (lane < 16) {
        const float4 self = *(const float4*)&g3[(long)r * OUT_CH + cl];
        const float d = dis[r];
        float4 o;
        o.x = (acc0.x + self.x) * d + b2[cl + 0];
        o.y = (acc0.y + self.y) * d + b2[cl + 1];
        o.z = (acc0.z + self.z) * d + b2[cl + 2];
        o.w = (acc0.w + self.w) * d + b2[cl + 3];
        *(float4*)&out[(long)r * OUT_CH + cl] = o;
    }
}

// ================= launch =================

extern "C" void kernel_launch(void* const* d_in, const int* in_sizes, int n_in,
                              void* d_out, int out_size, void* d_ws, size_t ws_size,
                              hipStream_t stream) {
    const float* x   = (const float*)d_in[0];
    const int*   ei  = (const int*)d_in[1];
    const float* W1  = (const float*)d_in[2];
    const float* b1  = (const float*)d_in[3];
    const float* W2  = (const float*)d_in[4];
    const float* b2  = (const float*)d_in[5];
    float* out = (float*)d_out;

    const int* src = ei;
    const int* dst = ei + N_EDGES;

    char* p = (char*)d_ws;
    int* cnt     = (int*)p;              p += 50048 * 4;
    int* row_ptr = (int*)p;              p += 50064 * 4;
    int* col     = (int*)p;              p += 800000 * 4;
    float* dis   = (float*)p;            p += 50048 * 4;
    float* g1    = (float*)p;            p += (long)N_NODES * HID * 4;
    float* a1    = (float*)p;            p += (long)N_NODES * HID * 4;
    float* g3    = (float*)p;

    const int B = 256;

    k_zero<<<(N_NODES + B - 1) / B, B, 0, stream>>>(cnt);
    k_hist<<<(N_EDGES + B - 1) / B, B, 0, stream>>>(dst, cnt);
    k_scan<<<1, 1024, 0, stream>>>(cnt, row_ptr);
    k_dis<<<(N_NODES + B - 1) / B, B, 0, stream>>>(row_ptr, dis);
    k_fill<<<(N_EDGES + B - 1) / B, B, 0, stream>>>(src, dst, cnt, col);

    k_gemm1<<<dim3((N_NODES + 63) / 64, 2), B, 0, stream>>>(x, W1, dis, g1);
    k_agg1<<<(N_NODES + 3) / 4, B, 0, stream>>>(row_ptr, col, dis, g1, b1, a1);
    k_gemm2<<<dim3((N_NODES + 63) / 64, 1), B, 0, stream>>>(a1, W2, dis, g3);
    k_agg2<<<(N_NODES + 3) / 4, B, 0, stream>>>(row_ptr, col, dis, g3, b2, out);
}

// Round 4
// 329.835 us; speedup vs baseline: 7.0148x; 1.2341x over previous
//
#include <hip/hip_runtime.h>

#define N_NODES 50000
#define N_EDGES 800000
#define IN_CH   128
#define HID     128
#define OUT_CH  64

#define SCAN_CHUNK  1024
#define SCAN_BLOCKS ((N_NODES + SCAN_CHUNK - 1) / SCAN_CHUNK)   // 49

// ================= CSR build =================

__global__ void k_zero(int* __restrict__ cnt) {
    int i = blockIdx.x * blockDim.x + threadIdx.x;
    if (i < N_NODES) cnt[i] = 0;
}

__global__ void k_hist(const int* __restrict__ dst, int* __restrict__ cnt) {
    int i = blockIdx.x * blockDim.x + threadIdx.x;
    if (i < N_EDGES) atomicAdd(&cnt[dst[i]], 1);
}

// ---- hierarchical scan, phase A: per-block (1024-elem chunk) reduction ----
__global__ __launch_bounds__(256) void k_scan_a(const int* __restrict__ cnt,
                                                int* __restrict__ bsum) {
    int base = blockIdx.x * SCAN_CHUNK + threadIdx.x * 4;
    int s = 0;
#pragma unroll
    for (int k = 0; k < 4; ++k) {
        int i = base + k;
        if (i < N_NODES) s += cnt[i];
    }
    for (int off = 32; off > 0; off >>= 1) s += __shfl_down(s, off);
    __shared__ int ws[4];
    int wave = threadIdx.x >> 6, lane = threadIdx.x & 63;
    if (lane == 0) ws[wave] = s;
    __syncthreads();
    if (threadIdx.x == 0) bsum[blockIdx.x] = ws[0] + ws[1] + ws[2] + ws[3];
}

// ---- phase B: one wave exclusive-scans the 49 block sums in place ----
__global__ __launch_bounds__(64) void k_scan_b(int* __restrict__ bsum) {
    int i = threadIdx.x;
    int v = (i < SCAN_BLOCKS) ? bsum[i] : 0;
    int incl = v;
    for (int off = 1; off < 64; off <<= 1) {
        int t = __shfl_up(incl, off);
        if (i >= off) incl += t;
    }
    if (i < SCAN_BLOCKS) bsum[i] = incl - v;
}

// ---- phase C: local exclusive scan + block offset; writes row_ptr, cursor, dis ----
__global__ __launch_bounds__(256) void k_scan_c(int* __restrict__ cnt,
                                                const int* __restrict__ boff,
                                                int* __restrict__ row_ptr,
                                                float* __restrict__ dis) {
    int base = blockIdx.x * SCAN_CHUNK + threadIdx.x * 4;
    int v[4];
#pragma unroll
    for (int k = 0; k < 4; ++k) {
        int i = base + k;
        v[k] = (i < N_NODES) ? cnt[i] : 0;
    }
    int p[4];
    p[0] = 0; p[1] = v[0]; p[2] = p[1] + v[1]; p[3] = p[2] + v[2];
    int tsum = p[3] + v[3];
    int lane = threadIdx.x & 63;
    int incl = tsum;
    for (int off = 1; off < 64; off <<= 1) {
        int t = __shfl_up(incl, off);
        if (lane >= off) incl += t;
    }
    int excl = incl - tsum;
    __shared__ int ws[4];
    int wave = threadIdx.x >> 6;
    if (lane == 63) ws[wave] = incl;
    __syncthreads();
    int woff = 0;
    for (int w = 0; w < wave; ++w) woff += ws[w];
    int off0 = boff[blockIdx.x] + woff + excl;
#pragma unroll
    for (int k = 0; k < 4; ++k) {
        int i = base + k;
        if (i < N_NODES) {
            int rp = off0 + p[k];
            row_ptr[i] = rp;
            cnt[i] = rp;                              // becomes fill cursor
            dis[i] = rsqrtf((float)v[k] + 1.0f);      // +1 self-loop
        }
    }
    if (blockIdx.x == 0 && threadIdx.x == 0) row_ptr[N_NODES] = N_EDGES;
}

__global__ void k_fill(const int* __restrict__ src, const int* __restrict__ dst,
                       int* __restrict__ cursor, int* __restrict__ col) {
    int e = blockIdx.x * blockDim.x + threadIdx.x;
    if (e < N_EDGES) {
        int pos = atomicAdd(&cursor[dst[e]], 1);
        col[pos] = src[e];
    }
}

// ================= register-tiled GEMM1: g1 = (x @ W1) * dis[row] =================
// 64 rows x 64 cols per block; 256 threads, 4x4 micro-tile each.

__global__ __launch_bounds__(256, 2) void k_gemm1(const float* __restrict__ x,
                                                  const float* __restrict__ W,
                                                  const float* __restrict__ dis,
                                                  float* __restrict__ g) {
    __shared__ float xs[64][132];     // padded: conflict-free row reads
    __shared__ float Ws[128][64];
    const int row0 = blockIdx.x * 64;
    const int c0   = blockIdx.y * 64;
    const int tid  = threadIdx.x;

    for (int i = tid; i < 64 * 32; i += 256) {
        int r = i >> 5, k4 = (i & 31) << 2;
        int gr = row0 + r;
        float4 v = make_float4(0.f, 0.f, 0.f, 0.f);
        if (gr < N_NODES) v = *(const float4*)&x[(long)gr * IN_CH + k4];
        *(float4*)&xs[r][k4] = v;
    }
    for (int i = tid; i < 128 * 16; i += 256) {
        int k = i >> 4, c4 = (i & 15) << 2;
        *(float4*)&Ws[k][c4] = *(const float4*)&W[k * HID + c0 + c4];
    }
    __syncthreads();

    const int tr = tid >> 4, tc = tid & 15;
    const int r0 = tr << 2, cc0 = tc << 2;

    float acc[16] = {};
    for (int k = 0; k < 128; k += 4) {
        float4 A[4], B[4];
#pragma unroll
        for (int i = 0; i < 4; ++i) A[i] = *(const float4*)&xs[r0 + i][k];
#pragma unroll
        for (int kk = 0; kk < 4; ++kk) B[kk] = *(const float4*)&Ws[k + kk][cc0];
        const float* a = (const float*)A;
        const float* b = (const float*)B;
#pragma unroll
        for (int i = 0; i < 4; ++i)
#pragma unroll
            for (int j = 0; j < 4; ++j)
#pragma unroll
                for (int kk = 0; kk < 4; ++kk)
                    acc[i * 4 + j] = fmaf(a[i * 4 + kk], b[kk * 4 + j], acc[i * 4 + j]);
    }

#pragma unroll
    for (int i = 0; i < 4; ++i) {
        int gr = row0 + r0 + i;
        if (gr < N_NODES) {
            float d = dis[gr];
            float4 o = make_float4(acc[i * 4 + 0] * d, acc[i * 4 + 1] * d,
                                   acc[i * 4 + 2] * d, acc[i * 4 + 3] * d);
            *(float4*)&g[(long)gr * HID + c0 + cc0] = o;
        }
    }
}

// ================= register-tiled GEMM2: g3 = (a1 @ W2) * dis[row] =================

__global__ __launch_bounds__(256, 2) void k_gemm2(const float* __restrict__ a1,
                                                  const float* __restrict__ W,
                                                  const float* __restrict__ dis,
                                                  float* __restrict__ g) {
    __shared__ float xs[64][132];
    __shared__ float Ws[128][64];
    const int row0 = blockIdx.x * 64;
    const int tid  = threadIdx.x;

    for (int i = tid; i < 64 * 32; i += 256) {
        int r = i >> 5, k4 = (i & 31) << 2;
        int gr = row0 + r;
        float4 v = make_float4(0.f, 0.f, 0.f, 0.f);
        if (gr < N_NODES) v = *(const float4*)&a1[(long)gr * HID + k4];
        *(float4*)&xs[r][k4] = v;
    }
    for (int i = tid; i < 128 * 16; i += 256) {
        int k = i >> 4, c4 = (i & 15) << 2;
        *(float4*)&Ws[k][c4] = *(const float4*)&W[k * OUT_CH + c4];
    }
    __syncthreads();

    const int tr = tid >> 4, tc = tid & 15;
    const int r0 = tr << 2, cc0 = tc << 2;

    float acc[16] = {};
    for (int k = 0; k < 128; k += 4) {
        float4 A[4], B[4];
#pragma unroll
        for (int i = 0; i < 4; ++i) A[i] = *(const float4*)&xs[r0 + i][k];
#pragma unroll
        for (int kk = 0; kk < 4; ++kk) B[kk] = *(const float4*)&Ws[k + kk][cc0];
        const float* a = (const float*)A;
        const float* b = (const float*)B;
#pragma unroll
        for (int i = 0; i < 4; ++i)
#pragma unroll
            for (int j = 0; j < 4; ++j)
#pragma unroll
                for (int kk = 0; kk < 4; ++kk)
                    acc[i * 4 + j] = fmaf(a[i * 4 + kk], b[kk * 4 + j], acc[i * 4 + j]);
    }

#pragma unroll
    for (int i = 0; i < 4; ++i) {
        int gr = row0 + r0 + i;
        if (gr < N_NODES) {
            float d = dis[gr];
            float4 o = make_float4(acc[i * 4 + 0] * d, acc[i * 4 + 1] * d,
                                   acc[i * 4 + 2] * d, acc[i * 4 + 3] * d);
            *(float4*)&g[(long)gr * OUT_CH + cc0] = o;
        }
    }
}

// ===== layer-1 aggregate: a1 = relu(dis[r]*(g1[r] + sum g1[src]) + b1) =====

__global__ __launch_bounds__(256) void k_agg1(const int* __restrict__ row_ptr,
                                              const int* __restrict__ col,
                                              const float* __restrict__ dis,
                                              const float* __restrict__ g1,
                                              const float* __restrict__ b1,
                                              float* __restrict__ a1) {
    int r = blockIdx.x * 4 + (threadIdx.x >> 6);
    if (r >= N_NODES) return;
    const int lane = threadIdx.x & 63;
    const int half = lane >> 5;
    const int cl = (lane & 31) << 2;
    const int beg = row_ptr[r], end = row_ptr[r + 1];

    float4 acc0 = make_float4(0.f, 0.f, 0.f, 0.f);
    float4 acc1 = make_float4(0.f, 0.f, 0.f, 0.f);
    int e = beg + half;
    for (; e + 2 < end; e += 4) {
        int s0 = col[e], s1 = col[e + 2];
        const float4 v0 = *(const float4*)&g1[(long)s0 * HID + cl];
        const float4 v1 = *(const float4*)&g1[(long)s1 * HID + cl];
        acc0.x += v0.x; acc0.y += v0.y; acc0.z += v0.z; acc0.w += v0.w;
        acc1.x += v1.x; acc1.y += v1.y; acc1.z += v1.z; acc1.w += v1.w;
    }
    if (e < end) {
        int s = col[e];
        const float4 v = *(const float4*)&g1[(long)s * HID + cl];
        acc0.x += v.x; acc0.y += v.y; acc0.z += v.z; acc0.w += v.w;
    }
    acc0.x += acc1.x; acc0.y += acc1.y; acc0.z += acc1.z; acc0.w += acc1.w;

    acc0.x += __shfl_down(acc0.x, 32);
    acc0.y += __shfl_down(acc0.y, 32);
    acc0.z += __shfl_down(acc0.z, 32);
    acc0.w += __shfl_down(acc0.w, 32);

    if (half == 0) {
        const float4 self = *(const float4*)&g1[(long)r * HID + cl];
        const float d = dis[r];
        float4 o;
        o.x = fmaxf((acc0.x + self.x) * d + b1[cl + 0], 0.f);
        o.y = fmaxf((acc0.y + self.y) * d + b1[cl + 1], 0.f);
        o.z = fmaxf((acc0.z + self.z) * d + b1[cl + 2], 0.f);
        o.w = fmaxf((acc0.w + self.w) * d + b1[cl + 3], 0.f);
        *(float4*)&a1[(long)r * HID + cl] = o;
    }
}

// ===== layer-2 aggregate: out = dis[r]*(g3[r] + sum g3[src]) + b2 =====

__global__ __launch_bounds__(256) void k_agg2(const int* __restrict__ row_ptr,
                                              const int* __restrict__ col,
                                              const float* __restrict__ dis,
                                              const float* __restrict__ g3,
                                              const float* __restrict__ b2,
                                              float* __restrict__ out) {
    int r = blockIdx.x * 4 + (threadIdx.x >> 6);
    if (r >= N_NODES) return;
    const int lane = threadIdx.x & 63;
    const int q = lane >> 4;
    const int cl = (lane & 15) << 2;
    const int beg = row_ptr[r], end = row_ptr[r + 1];

    float4 acc0 = make_float4(0.f, 0.f, 0.f, 0.f);
    float4 acc1 = make_float4(0.f, 0.f, 0.f, 0.f);
    int e = beg + q;
    for (; e + 4 < end; e += 8) {
        int s0 = col[e], s1 = col[e + 4];
        const float4 v0 = *(const float4*)&g3[(long)s0 * OUT_CH + cl];
        const float4 v1 = *(const float4*)&g3[(long)s1 * OUT_CH + cl];
        acc0.x += v0.x; acc0.y += v0.y; acc0.z += v0.z; acc0.w += v0.w;
        acc1.x += v1.x; acc1.y += v1.y; acc1.z += v1.z; acc1.w += v1.w;
    }
    if (e < end) {
        int s = col[e];
        const float4 v = *(const float4*)&g3[(long)s * OUT_CH + cl];
        acc0.x += v.x; acc0.y += v.y; acc0.z += v.z; acc0.w += v.w;
    }
    acc0.x += acc1.x; acc0.y += acc1.y; acc0.z += acc1.z; acc0.w += acc1.w;

    acc0.x += __shfl_down(acc0.x, 32);
    acc0.y += __shfl_down(acc0.y, 32);
    acc0.z += __shfl_down(acc0.z, 32);
    acc0.w += __shfl_down(acc0.w, 32);
    acc0.x += __shfl_down(acc0.x, 16);
    acc0.y += __shfl_down(acc0.y, 16);
    acc0.z += __shfl_down(acc0.z, 16);
    acc0.w += __shfl_down(acc0.w, 16);

    if (lane < 16) {
        const float4 self = *(const float4*)&g3[(long)r * OUT_CH + cl];
        const float d = dis[r];
        float4 o;
        o.x = (acc0.x + self.x) * d + b2[cl + 0];
        o.y = (acc0.y + self.y) * d + b2[cl + 1];
        o.z = (acc0.z + self.z) * d + b2[cl + 2];
        o.w = (acc0.w + self.w) * d + b2[cl + 3];
        *(float4*)&out[(long)r * OUT_CH + cl] = o;
    }
}

// ================= launch =================

extern "C" void kernel_launch(void* const* d_in, const int* in_sizes, int n_in,
                              void* d_out, int out_size, void* d_ws, size_t ws_size,
                              hipStream_t stream) {
    const float* x   = (const float*)d_in[0];
    const int*   ei  = (const int*)d_in[1];
    const float* W1  = (const float*)d_in[2];
    const float* b1  = (const float*)d_in[3];
    const float* W2  = (const float*)d_in[4];
    const float* b2  = (const float*)d_in[5];
    float* out = (float*)d_out;

    const int* src = ei;
    const int* dst = ei + N_EDGES;

    char* p = (char*)d_ws;
    int* cnt     = (int*)p;              p += 50048 * 4;
    int* row_ptr = (int*)p;              p += 50064 * 4;
    int* col     = (int*)p;              p += 800000 * 4;
    int* bsum    = (int*)p;              p += 64 * 4;
    float* dis   = (float*)p;            p += 50048 * 4;
    float* g1    = (float*)p;            p += (long)N_NODES * HID * 4;
    float* a1    = (float*)p;            p += (long)N_NODES * HID * 4;
    float* g3    = (float*)p;

    const int B = 256;

    k_zero<<<(N_NODES + B - 1) / B, B, 0, stream>>>(cnt);
    k_hist<<<(N_EDGES + B - 1) / B, B, 0, stream>>>(dst, cnt);
    k_scan_a<<<SCAN_BLOCKS, B, 0, stream>>>(cnt, bsum);
    k_scan_b<<<1, 64, 0, stream>>>(bsum);
    k_scan_c<<<SCAN_BLOCKS, B, 0, stream>>>(cnt, bsum, row_ptr, dis);
    k_fill<<<(N_EDGES + B - 1) / B, B, 0, stream>>>(src, dst, cnt, col);

    k_gemm1<<<dim3((N_NODES + 63) / 64, 2), B, 0, stream>>>(x, W1, dis, g1);
    k_agg1<<<(N_NODES + 3) / 4, B, 0, stream>>>(row_ptr, col, dis, g1, b1, a1);
    k_gemm2<<<dim3((N_NODES + 63) / 64, 1), B, 0, stream>>>(a1, W2, dis, g3);
    k_agg2<<<(N_NODES + 3) / 4, B, 0, stream>>>(row_ptr, col, dis, g3, b2, out);
}

// Round 5
// 290.263 us; speedup vs baseline: 7.9711x; 1.1363x over previous
//
#include <hip/hip_runtime.h>

#define N_NODES 50000
#define N_EDGES 800000
#define IN_CH   128
#define HID     128
#define OUT_CH  64

#define SCAN_CHUNK  1024
#define SCAN_BLOCKS ((N_NODES + SCAN_CHUNK - 1) / SCAN_CHUNK)   // 49

__device__ __forceinline__ unsigned short f2bf(float f) {
    unsigned u = __float_as_uint(f);
    u += 0x7fffu + ((u >> 16) & 1u);      // round-to-nearest-even
    return (unsigned short)(u >> 16);
}
__device__ __forceinline__ float bf_lo(unsigned u) { return __uint_as_float(u << 16); }
__device__ __forceinline__ float bf_hi(unsigned u) { return __uint_as_float(u & 0xffff0000u); }

// ================= CSR build =================

__global__ void k_zero(int* __restrict__ cnt) {
    int i = blockIdx.x * blockDim.x + threadIdx.x;
    if (i < N_NODES) cnt[i] = 0;
}

__global__ void k_hist(const int* __restrict__ dst, int* __restrict__ cnt) {
    int i = blockIdx.x * blockDim.x + threadIdx.x;
    if (i < N_EDGES) atomicAdd(&cnt[dst[i]], 1);
}

__global__ __launch_bounds__(256) void k_scan_a(const int* __restrict__ cnt,
                                                int* __restrict__ bsum) {
    int base = blockIdx.x * SCAN_CHUNK + threadIdx.x * 4;
    int s = 0;
#pragma unroll
    for (int k = 0; k < 4; ++k) {
        int i = base + k;
        if (i < N_NODES) s += cnt[i];
    }
    for (int off = 32; off > 0; off >>= 1) s += __shfl_down(s, off);
    __shared__ int ws[4];
    int wave = threadIdx.x >> 6, lane = threadIdx.x & 63;
    if (lane == 0) ws[wave] = s;
    __syncthreads();
    if (threadIdx.x == 0) bsum[blockIdx.x] = ws[0] + ws[1] + ws[2] + ws[3];
}

__global__ __launch_bounds__(64) void k_scan_b(int* __restrict__ bsum) {
    int i = threadIdx.x;
    int v = (i < SCAN_BLOCKS) ? bsum[i] : 0;
    int incl = v;
    for (int off = 1; off < 64; off <<= 1) {
        int t = __shfl_up(incl, off);
        if (i >= off) incl += t;
    }
    if (i < SCAN_BLOCKS) bsum[i] = incl - v;
}

__global__ __launch_bounds__(256) void k_scan_c(int* __restrict__ cnt,
                                                const int* __restrict__ boff,
                                                int* __restrict__ row_ptr,
                                                float* __restrict__ dis) {
    int base = blockIdx.x * SCAN_CHUNK + threadIdx.x * 4;
    int v[4];
#pragma unroll
    for (int k = 0; k < 4; ++k) {
        int i = base + k;
        v[k] = (i < N_NODES) ? cnt[i] : 0;
    }
    int p[4];
    p[0] = 0; p[1] = v[0]; p[2] = p[1] + v[1]; p[3] = p[2] + v[2];
    int tsum = p[3] + v[3];
    int lane = threadIdx.x & 63;
    int incl = tsum;
    for (int off = 1; off < 64; off <<= 1) {
        int t = __shfl_up(incl, off);
        if (lane >= off) incl += t;
    }
    int excl = incl - tsum;
    __shared__ int ws[4];
    int wave = threadIdx.x >> 6;
    if (lane == 63) ws[wave] = incl;
    __syncthreads();
    int woff = 0;
    for (int w = 0; w < wave; ++w) woff += ws[w];
    int off0 = boff[blockIdx.x] + woff + excl;
#pragma unroll
    for (int k = 0; k < 4; ++k) {
        int i = base + k;
        if (i < N_NODES) {
            int rp = off0 + p[k];
            row_ptr[i] = rp;
            cnt[i] = rp;
            dis[i] = rsqrtf((float)v[k] + 1.0f);
        }
    }
    if (blockIdx.x == 0 && threadIdx.x == 0) row_ptr[N_NODES] = N_EDGES;
}

__global__ void k_fill(const int* __restrict__ src, const int* __restrict__ dst,
                       int* __restrict__ cursor, int* __restrict__ col) {
    int e = blockIdx.x * blockDim.x + threadIdx.x;
    if (e < N_EDGES) {
        int pos = atomicAdd(&cursor[dst[e]], 1);
        col[pos] = src[e];
    }
}

// ====== GEMM1: g1 = bf16((x @ W1) * dis[row]), 64x64 tile, 4x4 micro-tile ======

__global__ __launch_bounds__(256, 2) void k_gemm1(const float* __restrict__ x,
                                                  const float* __restrict__ W,
                                                  const float* __restrict__ dis,
                                                  unsigned short* __restrict__ g) {
    __shared__ float xs[64][132];
    __shared__ float Ws[128][64];
    const int row0 = blockIdx.x * 64;
    const int c0   = blockIdx.y * 64;
    const int tid  = threadIdx.x;

    for (int i = tid; i < 64 * 32; i += 256) {
        int r = i >> 5, k4 = (i & 31) << 2;
        int gr = row0 + r;
        float4 v = make_float4(0.f, 0.f, 0.f, 0.f);
        if (gr < N_NODES) v = *(const float4*)&x[(long)gr * IN_CH + k4];
        *(float4*)&xs[r][k4] = v;
    }
    for (int i = tid; i < 128 * 16; i += 256) {
        int k = i >> 4, c4 = (i & 15) << 2;
        *(float4*)&Ws[k][c4] = *(const float4*)&W[k * HID + c0 + c4];
    }
    __syncthreads();

    const int tr = tid >> 4, tc = tid & 15;
    const int r0 = tr << 2, cc0 = tc << 2;

    float acc[16] = {};
    for (int k = 0; k < 128; k += 4) {
        float4 A[4], B[4];
#pragma unroll
        for (int i = 0; i < 4; ++i) A[i] = *(const float4*)&xs[r0 + i][k];
#pragma unroll
        for (int kk = 0; kk < 4; ++kk) B[kk] = *(const float4*)&Ws[k + kk][cc0];
        const float* a = (const float*)A;
        const float* b = (const float*)B;
#pragma unroll
        for (int i = 0; i < 4; ++i)
#pragma unroll
            for (int j = 0; j < 4; ++j)
#pragma unroll
                for (int kk = 0; kk < 4; ++kk)
                    acc[i * 4 + j] = fmaf(a[i * 4 + kk], b[kk * 4 + j], acc[i * 4 + j]);
    }

#pragma unroll
    for (int i = 0; i < 4; ++i) {
        int gr = row0 + r0 + i;
        if (gr < N_NODES) {
            float d = dis[gr];
            ushort4 o;
            o.x = f2bf(acc[i * 4 + 0] * d);
            o.y = f2bf(acc[i * 4 + 1] * d);
            o.z = f2bf(acc[i * 4 + 2] * d);
            o.w = f2bf(acc[i * 4 + 3] * d);
            *(ushort4*)&g[(long)gr * HID + c0 + cc0] = o;
        }
    }
}

// ====== GEMM2: g3 = bf16((a1 @ W2) * dis[row]) ======

__global__ __launch_bounds__(256, 2) void k_gemm2(const float* __restrict__ a1,
                                                  const float* __restrict__ W,
                                                  const float* __restrict__ dis,
                                                  unsigned short* __restrict__ g) {
    __shared__ float xs[64][132];
    __shared__ float Ws[128][64];
    const int row0 = blockIdx.x * 64;
    const int tid  = threadIdx.x;

    for (int i = tid; i < 64 * 32; i += 256) {
        int r = i >> 5, k4 = (i & 31) << 2;
        int gr = row0 + r;
        float4 v = make_float4(0.f, 0.f, 0.f, 0.f);
        if (gr < N_NODES) v = *(const float4*)&a1[(long)gr * HID + k4];
        *(float4*)&xs[r][k4] = v;
    }
    for (int i = tid; i < 128 * 16; i += 256) {
        int k = i >> 4, c4 = (i & 15) << 2;
        *(float4*)&Ws[k][c4] = *(const float4*)&W[k * OUT_CH + c4];
    }
    __syncthreads();

    const int tr = tid >> 4, tc = tid & 15;
    const int r0 = tr << 2, cc0 = tc << 2;

    float acc[16] = {};
    for (int k = 0; k < 128; k += 4) {
        float4 A[4], B[4];
#pragma unroll
        for (int i = 0; i < 4; ++i) A[i] = *(const float4*)&xs[r0 + i][k];
#pragma unroll
        for (int kk = 0; kk < 4; ++kk) B[kk] = *(const float4*)&Ws[k + kk][cc0];
        const float* a = (const float*)A;
        const float* b = (const float*)B;
#pragma unroll
        for (int i = 0; i < 4; ++i)
#pragma unroll
            for (int j = 0; j < 4; ++j)
#pragma unroll
                for (int kk = 0; kk < 4; ++kk)
                    acc[i * 4 + j] = fmaf(a[i * 4 + kk], b[kk * 4 + j], acc[i * 4 + j]);
    }

#pragma unroll
    for (int i = 0; i < 4; ++i) {
        int gr = row0 + r0 + i;
        if (gr < N_NODES) {
            float d = dis[gr];
            ushort4 o;
            o.x = f2bf(acc[i * 4 + 0] * d);
            o.y = f2bf(acc[i * 4 + 1] * d);
            o.z = f2bf(acc[i * 4 + 2] * d);
            o.w = f2bf(acc[i * 4 + 3] * d);
            *(ushort4*)&g[(long)gr * OUT_CH + cc0] = o;
        }
    }
}

// ===== layer-1 aggregate (bf16 gather, fp32 acc) =====
// wave per row; 4 edge-slots (16 lanes x 16B = one 256B bf16 row); 2-deep unroll.

__global__ __launch_bounds__(256) void k_agg1(const int* __restrict__ row_ptr,
                                              const int* __restrict__ col,
                                              const float* __restrict__ dis,
                                              const unsigned short* __restrict__ g1,
                                              const float* __restrict__ b1,
                                              float* __restrict__ a1) {
    int r = blockIdx.x * 4 + (threadIdx.x >> 6);
    if (r >= N_NODES) return;
    const int lane = threadIdx.x & 63;
    const int q = lane >> 4;            // edge slot 0..3
    const int seg = lane & 15;          // 16B segment within row
    const int cl = seg << 3;            // channel base (8 ch/lane)
    const uint4* G = (const uint4*)g1;  // row = 16 x uint4
    const int beg = row_ptr[r], end = row_ptr[r + 1];

    float acc[8] = {};
    int e = beg + q;
    for (; e + 4 < end; e += 8) {
        int s0 = col[e], s1 = col[e + 4];
        uint4 u0 = G[(long)s0 * 16 + seg];
        uint4 u1 = G[(long)s1 * 16 + seg];
        acc[0] += bf_lo(u0.x); acc[1] += bf_hi(u0.x);
        acc[2] += bf_lo(u0.y); acc[3] += bf_hi(u0.y);
        acc[4] += bf_lo(u0.z); acc[5] += bf_hi(u0.z);
        acc[6] += bf_lo(u0.w); acc[7] += bf_hi(u0.w);
        acc[0] += bf_lo(u1.x); acc[1] += bf_hi(u1.x);
        acc[2] += bf_lo(u1.y); acc[3] += bf_hi(u1.y);
        acc[4] += bf_lo(u1.z); acc[5] += bf_hi(u1.z);
        acc[6] += bf_lo(u1.w); acc[7] += bf_hi(u1.w);
    }
    if (e < end) {
        int s = col[e];
        uint4 u = G[(long)s * 16 + seg];
        acc[0] += bf_lo(u.x); acc[1] += bf_hi(u.x);
        acc[2] += bf_lo(u.y); acc[3] += bf_hi(u.y);
        acc[4] += bf_lo(u.z); acc[5] += bf_hi(u.z);
        acc[6] += bf_lo(u.w); acc[7] += bf_hi(u.w);
    }
#pragma unroll
    for (int off = 16; off < 64; off <<= 1)
#pragma unroll
        for (int j = 0; j < 8; ++j) acc[j] += __shfl_xor(acc[j], off);

    if (q == 0) {
        uint4 u = G[(long)r * 16 + seg];    // self-loop term
        acc[0] += bf_lo(u.x); acc[1] += bf_hi(u.x);
        acc[2] += bf_lo(u.y); acc[3] += bf_hi(u.y);
        acc[4] += bf_lo(u.z); acc[5] += bf_hi(u.z);
        acc[6] += bf_lo(u.w); acc[7] += bf_hi(u.w);
        const float d = dis[r];
        float4 o0, o1;
        o0.x = fmaxf(acc[0] * d + b1[cl + 0], 0.f);
        o0.y = fmaxf(acc[1] * d + b1[cl + 1], 0.f);
        o0.z = fmaxf(acc[2] * d + b1[cl + 2], 0.f);
        o0.w = fmaxf(acc[3] * d + b1[cl + 3], 0.f);
        o1.x = fmaxf(acc[4] * d + b1[cl + 4], 0.f);
        o1.y = fmaxf(acc[5] * d + b1[cl + 5], 0.f);
        o1.z = fmaxf(acc[6] * d + b1[cl + 6], 0.f);
        o1.w = fmaxf(acc[7] * d + b1[cl + 7], 0.f);
        *(float4*)&a1[(long)r * HID + cl] = o0;
        *(float4*)&a1[(long)r * HID + cl + 4] = o1;
    }
}

// ===== layer-2 aggregate (bf16 gather, fp32 acc) =====
// wave per row; 8 edge-slots (8 lanes x 16B = one 128B bf16 row); 2-deep unroll.

__global__ __launch_bounds__(256) void k_agg2(const int* __restrict__ row_ptr,
                                              const int* __restrict__ col,
                                              const float* __restrict__ dis,
                                              const unsigned short* __restrict__ g3,
                                              const float* __restrict__ b2,
                                              float* __restrict__ out) {
    int r = blockIdx.x * 4 + (threadIdx.x >> 6);
    if (r >= N_NODES) return;
    const int lane = threadIdx.x & 63;
    const int q = lane >> 3;            // edge slot 0..7
    const int seg = lane & 7;           // 16B segment within row
    const int cl = seg << 3;            // channel base
    const uint4* G = (const uint4*)g3;  // row = 8 x uint4
    const int beg = row_ptr[r], end = row_ptr[r + 1];

    float acc[8] = {};
    int e = beg + q;
    for (; e + 8 < end; e += 16) {
        int s0 = col[e], s1 = col[e + 8];
        uint4 u0 = G[(long)s0 * 8 + seg];
        uint4 u1 = G[(long)s1 * 8 + seg];
        acc[0] += bf_lo(u0.x); acc[1] += bf_hi(u0.x);
        acc[2] += bf_lo(u0.y); acc[3] += bf_hi(u0.y);
        acc[4] += bf_lo(u0.z); acc[5] += bf_hi(u0.z);
        acc[6] += bf_lo(u0.w); acc[7] += bf_hi(u0.w);
        acc[0] += bf_lo(u1.x); acc[1] += bf_hi(u1.x);
        acc[2] += bf_lo(u1.y); acc[3] += bf_hi(u1.y);
        acc[4] += bf_lo(u1.z); acc[5] += bf_hi(u1.z);
        acc[6] += bf_lo(u1.w); acc[7] += bf_hi(u1.w);
    }
    if (e < end) {
        int s = col[e];
        uint4 u = G[(long)s * 8 + seg];
        acc[0] += bf_lo(u.x); acc[1] += bf_hi(u.x);
        acc[2] += bf_lo(u.y); acc[3] += bf_hi(u.y);
        acc[4] += bf_lo(u.z); acc[5] += bf_hi(u.z);
        acc[6] += bf_lo(u.w); acc[7] += bf_hi(u.w);
    }
#pragma unroll
    for (int off = 8; off < 64; off <<= 1)
#pragma unroll
        for (int j = 0; j < 8; ++j) acc[j] += __shfl_xor(acc[j], off);

    if (q == 0) {
        uint4 u = G[(long)r * 8 + seg];     // self-loop term
        acc[0] += bf_lo(u.x); acc[1] += bf_hi(u.x);
        acc[2] += bf_lo(u.y); acc[3] += bf_hi(u.y);
        acc[4] += bf_lo(u.z); acc[5] += bf_hi(u.z);
        acc[6] += bf_lo(u.w); acc[7] += bf_hi(u.w);
        const float d = dis[r];
        float4 o0, o1;
        o0.x = acc[0] * d + b2[cl + 0];
        o0.y = acc[1] * d + b2[cl + 1];
        o0.z = acc[2] * d + b2[cl + 2];
        o0.w = acc[3] * d + b2[cl + 3];
        o1.x = acc[4] * d + b2[cl + 4];
        o1.y = acc[5] * d + b2[cl + 5];
        o1.z = acc[6] * d + b2[cl + 6];
        o1.w = acc[7] * d + b2[cl + 7];
        *(float4*)&out[(long)r * OUT_CH + cl] = o0;
        *(float4*)&out[(long)r * OUT_CH + cl + 4] = o1;
    }
}

// ================= launch =================

extern "C" void kernel_launch(void* const* d_in, const int* in_sizes, int n_in,
                              void* d_out, int out_size, void* d_ws, size_t ws_size,
                              hipStream_t stream) {
    const float* x   = (const float*)d_in[0];
    const int*   ei  = (const int*)d_in[1];
    const float* W1  = (const float*)d_in[2];
    const float* b1  = (const float*)d_in[3];
    const float* W2  = (const float*)d_in[4];
    const float* b2  = (const float*)d_in[5];
    float* out = (float*)d_out;

    const int* src = ei;
    const int* dst = ei + N_EDGES;

    char* p = (char*)d_ws;
    int* cnt     = (int*)p;               p += 50048 * 4;
    int* row_ptr = (int*)p;               p += 50064 * 4;
    int* col     = (int*)p;               p += 800000 * 4;
    int* bsum    = (int*)p;               p += 64 * 4;
    float* dis   = (float*)p;             p += 50048 * 4;
    unsigned short* g1 = (unsigned short*)p;  p += (long)N_NODES * HID * 2;
    float* a1    = (float*)p;             p += (long)N_NODES * HID * 4;
    unsigned short* g3 = (unsigned short*)p;

    const int B = 256;

    k_zero<<<(N_NODES + B - 1) / B, B, 0, stream>>>(cnt);
    k_hist<<<(N_EDGES + B - 1) / B, B, 0, stream>>>(dst, cnt);
    k_scan_a<<<SCAN_BLOCKS, B, 0, stream>>>(cnt, bsum);
    k_scan_b<<<1, 64, 0, stream>>>(bsum);
    k_scan_c<<<SCAN_BLOCKS, B, 0, stream>>>(cnt, bsum, row_ptr, dis);
    k_fill<<<(N_EDGES + B - 1) / B, B, 0, stream>>>(src, dst, cnt, col);

    k_gemm1<<<dim3((N_NODES + 63) / 64, 2), B, 0, stream>>>(x, W1, dis, g1);
    k_agg1<<<(N_NODES + 3) / 4, B, 0, stream>>>(row_ptr, col, dis, g1, b1, a1);
    k_gemm2<<<dim3((N_NODES + 63) / 64, 1), B, 0, stream>>>(a1, W2, dis, g3);
    k_agg2<<<(N_NODES + 3) / 4, B, 0, stream>>>(row_ptr, col, dis, g3, b2, out);
}

// Round 6
// 243.041 us; speedup vs baseline: 9.5198x; 1.1943x over previous
//
#include <hip/hip_runtime.h>

#define N_NODES 50000
#define N_EDGES 800000
#define IN_CH   128
#define HID     128
#define OUT_CH  64

#define NBUCK 196          // ceil(50000/256) dst buckets
#define BUCKW 256          // dst values per bucket

__device__ __forceinline__ unsigned short f2bf(float f) {
    unsigned u = __float_as_uint(f);
    u += 0x7fffu + ((u >> 16) & 1u);      // round-to-nearest-even
    return (unsigned short)(u >> 16);
}
__device__ __forceinline__ float bf_lo(unsigned u) { return __uint_as_float(u << 16); }
__device__ __forceinline__ float bf_hi(unsigned u) { return __uint_as_float(u & 0xffff0000u); }

// ================= CSR build: two-level bucket sort =================

__global__ void k_zero_small(int* __restrict__ bcnt) {
    if (threadIdx.x < NBUCK) bcnt[threadIdx.x] = 0;
}

// coarse 196-bin histogram of dst>>8, LDS-staged
__global__ __launch_bounds__(256) void kb_hist(const int* __restrict__ dst,
                                               int* __restrict__ bcnt) {
    __shared__ int lh[NBUCK];
    for (int i = threadIdx.x; i < NBUCK; i += 256) lh[i] = 0;
    __syncthreads();
    int base = blockIdx.x * 8192;
#pragma unroll 4
    for (int k = 0; k < 32; ++k) {
        int e = base + k * 256 + threadIdx.x;
        if (e < N_EDGES) atomicAdd(&lh[dst[e] >> 8], 1);
    }
    __syncthreads();
    for (int i = threadIdx.x; i < NBUCK; i += 256)
        if (lh[i]) atomicAdd(&bcnt[i], lh[i]);
}

// scan 196 bucket counts -> bucket base + cursor; also the row_ptr sentinel
__global__ __launch_bounds__(256) void kb_scan(const int* __restrict__ bcnt,
                                               int* __restrict__ bbase,
                                               int* __restrict__ bcur,
                                               int* __restrict__ row_ptr) {
    __shared__ int s[256];
    int t = threadIdx.x;
    int v = (t < NBUCK) ? bcnt[t] : 0;
    s[t] = v;
    __syncthreads();
    for (int off = 1; off < 256; off <<= 1) {
        int u = (t >= off) ? s[t - off] : 0;
        __syncthreads();
        s[t] += u;
        __syncthreads();
    }
    int excl = s[t] - v;
    if (t < NBUCK) { bbase[t] = excl; bcur[t] = excl; }
    if (t == 0) { bbase[NBUCK] = N_EDGES; row_ptr[N_NODES] = N_EDGES; }
}

// scatter (src,dst) records into bucket runs; per-block LDS count + one global
// reservation per touched bucket -> writes cluster into block-local runs.
__global__ __launch_bounds__(256) void kb_scatter(const int* __restrict__ src,
                                                  const int* __restrict__ dst,
                                                  int* __restrict__ bcur,
                                                  uint2* __restrict__ rec) {
    __shared__ int lh[NBUCK];
    __shared__ int gbase[NBUCK];
    for (int i = threadIdx.x; i < NBUCK; i += 256) lh[i] = 0;
    __syncthreads();
    int base = blockIdx.x * 4096;
#pragma unroll 4
    for (int k = 0; k < 16; ++k) {
        int e = base + k * 256 + threadIdx.x;
        if (e < N_EDGES) atomicAdd(&lh[dst[e] >> 8], 1);
    }
    __syncthreads();
    for (int i = threadIdx.x; i < NBUCK; i += 256) {
        int c = lh[i];
        gbase[i] = c ? atomicAdd(&bcur[i], c) : 0;
    }
    __syncthreads();
    for (int i = threadIdx.x; i < NBUCK; i += 256) lh[i] = 0;
    __syncthreads();
#pragma unroll 4
    for (int k = 0; k < 16; ++k) {
        int e = base + k * 256 + threadIdx.x;
        if (e < N_EDGES) {
            int d = dst[e], b = d >> 8;
            int rk = atomicAdd(&lh[b], 1);
            rec[gbase[b] + rk] = make_uint2((unsigned)src[e], (unsigned)d);
        }
    }
}

// each block owns one bucket (256 dsts): hist256 -> row_ptr/dis, then fill its
// private contiguous col slice with LDS cursors. No global atomics.
__global__ __launch_bounds__(256) void kc_csr(const int* __restrict__ bbase,
                                              const uint2* __restrict__ rec,
                                              int* __restrict__ row_ptr,
                                              float* __restrict__ dis,
                                              int* __restrict__ col) {
    __shared__ int lh[BUCKW];
    __shared__ int cur[BUCKW];
    __shared__ int s[BUCKW];
    const int b = blockIdx.x, t = threadIdx.x;
    const int lo = bbase[b], hi = bbase[b + 1];
    lh[t] = 0;
    __syncthreads();
    for (int j = lo + t; j < hi; j += 256)
        atomicAdd(&lh[(int)rec[j].y - (b << 8)], 1);
    __syncthreads();
    int deg = lh[t];
    s[t] = deg;
    __syncthreads();
    for (int off = 1; off < 256; off <<= 1) {
        int u = (t >= off) ? s[t - off] : 0;
        __syncthreads();
        s[t] += u;
        __syncthreads();
    }
    int gp = lo + s[t] - deg;
    int node = (b << 8) + t;
    if (node < N_NODES) {
        row_ptr[node] = gp;
        dis[node] = rsqrtf((float)deg + 1.0f);
    }
    cur[t] = gp;
    __syncthreads();
    for (int j = lo + t; j < hi; j += 256) {
        uint2 r = rec[j];
        int pos = atomicAdd(&cur[(int)r.y - (b << 8)], 1);
        col[pos] = (int)r.x;
    }
}

// ====== GEMM1: g1 = bf16((x @ W1) * dis[row]), 64x64 tile, 4x4 micro-tile ======

__global__ __launch_bounds__(256, 2) void k_gemm1(const float* __restrict__ x,
                                                  const float* __restrict__ W,
                                                  const float* __restrict__ dis,
                                                  unsigned short* __restrict__ g) {
    __shared__ float xs[64][132];
    __shared__ float Ws[128][64];
    const int row0 = blockIdx.x * 64;
    const int c0   = blockIdx.y * 64;
    const int tid  = threadIdx.x;

    for (int i = tid; i < 64 * 32; i += 256) {
        int r = i >> 5, k4 = (i & 31) << 2;
        int gr = row0 + r;
        float4 v = make_float4(0.f, 0.f, 0.f, 0.f);
        if (gr < N_NODES) v = *(const float4*)&x[(long)gr * IN_CH + k4];
        *(float4*)&xs[r][k4] = v;
    }
    for (int i = tid; i < 128 * 16; i += 256) {
        int k = i >> 4, c4 = (i & 15) << 2;
        *(float4*)&Ws[k][c4] = *(const float4*)&W[k * HID + c0 + c4];
    }
    __syncthreads();

    const int tr = tid >> 4, tc = tid & 15;
    const int r0 = tr << 2, cc0 = tc << 2;

    float acc[16] = {};
    for (int k = 0; k < 128; k += 4) {
        float4 A[4], B[4];
#pragma unroll
        for (int i = 0; i < 4; ++i) A[i] = *(const float4*)&xs[r0 + i][k];
#pragma unroll
        for (int kk = 0; kk < 4; ++kk) B[kk] = *(const float4*)&Ws[k + kk][cc0];
        const float* a = (const float*)A;
        const float* b = (const float*)B;
#pragma unroll
        for (int i = 0; i < 4; ++i)
#pragma unroll
            for (int j = 0; j < 4; ++j)
#pragma unroll
                for (int kk = 0; kk < 4; ++kk)
                    acc[i * 4 + j] = fmaf(a[i * 4 + kk], b[kk * 4 + j], acc[i * 4 + j]);
    }

#pragma unroll
    for (int i = 0; i < 4; ++i) {
        int gr = row0 + r0 + i;
        if (gr < N_NODES) {
            float d = dis[gr];
            ushort4 o;
            o.x = f2bf(acc[i * 4 + 0] * d);
            o.y = f2bf(acc[i * 4 + 1] * d);
            o.z = f2bf(acc[i * 4 + 2] * d);
            o.w = f2bf(acc[i * 4 + 3] * d);
            *(ushort4*)&g[(long)gr * HID + c0 + cc0] = o;
        }
    }
}

// ====== GEMM2: g3 = bf16((a1 @ W2) * dis[row]) ======

__global__ __launch_bounds__(256, 2) void k_gemm2(const float* __restrict__ a1,
                                                  const float* __restrict__ W,
                                                  const float* __restrict__ dis,
                                                  unsigned short* __restrict__ g) {
    __shared__ float xs[64][132];
    __shared__ float Ws[128][64];
    const int row0 = blockIdx.x * 64;
    const int tid  = threadIdx.x;

    for (int i = tid; i < 64 * 32; i += 256) {
        int r = i >> 5, k4 = (i & 31) << 2;
        int gr = row0 + r;
        float4 v = make_float4(0.f, 0.f, 0.f, 0.f);
        if (gr < N_NODES) v = *(const float4*)&a1[(long)gr * HID + k4];
        *(float4*)&xs[r][k4] = v;
    }
    for (int i = tid; i < 128 * 16; i += 256) {
        int k = i >> 4, c4 = (i & 15) << 2;
        *(float4*)&Ws[k][c4] = *(const float4*)&W[k * OUT_CH + c4];
    }
    __syncthreads();

    const int tr = tid >> 4, tc = tid & 15;
    const int r0 = tr << 2, cc0 = tc << 2;

    float acc[16] = {};
    for (int k = 0; k < 128; k += 4) {
        float4 A[4], B[4];
#pragma unroll
        for (int i = 0; i < 4; ++i) A[i] = *(const float4*)&xs[r0 + i][k];
#pragma unroll
        for (int kk = 0; kk < 4; ++kk) B[kk] = *(const float4*)&Ws[k + kk][cc0];
        const float* a = (const float*)A;
        const float* b = (const float*)B;
#pragma unroll
        for (int i = 0; i < 4; ++i)
#pragma unroll
            for (int j = 0; j < 4; ++j)
#pragma unroll
                for (int kk = 0; kk < 4; ++kk)
                    acc[i * 4 + j] = fmaf(a[i * 4 + kk], b[kk * 4 + j], acc[i * 4 + j]);
    }

#pragma unroll
    for (int i = 0; i < 4; ++i) {
        int gr = row0 + r0 + i;
        if (gr < N_NODES) {
            float d = dis[gr];
            ushort4 o;
            o.x = f2bf(acc[i * 4 + 0] * d);
            o.y = f2bf(acc[i * 4 + 1] * d);
            o.z = f2bf(acc[i * 4 + 2] * d);
            o.w = f2bf(acc[i * 4 + 3] * d);
            *(ushort4*)&g[(long)gr * OUT_CH + cc0] = o;
        }
    }
}

// ===== layer-1 aggregate (bf16 gather, fp32 acc) =====

__global__ __launch_bounds__(256) void k_agg1(const int* __restrict__ row_ptr,
                                              const int* __restrict__ col,
                                              const float* __restrict__ dis,
                                              const unsigned short* __restrict__ g1,
                                              const float* __restrict__ b1,
                                              float* __restrict__ a1) {
    int r = blockIdx.x * 4 + (threadIdx.x >> 6);
    if (r >= N_NODES) return;
    const int lane = threadIdx.x & 63;
    const int q = lane >> 4;
    const int seg = lane & 15;
    const int cl = seg << 3;
    const uint4* G = (const uint4*)g1;
    const int beg = row_ptr[r], end = row_ptr[r + 1];

    float acc[8] = {};
    int e = beg + q;
    for (; e + 4 < end; e += 8) {
        int s0 = col[e], s1 = col[e + 4];
        uint4 u0 = G[(long)s0 * 16 + seg];
        uint4 u1 = G[(long)s1 * 16 + seg];
        acc[0] += bf_lo(u0.x); acc[1] += bf_hi(u0.x);
        acc[2] += bf_lo(u0.y); acc[3] += bf_hi(u0.y);
        acc[4] += bf_lo(u0.z); acc[5] += bf_hi(u0.z);
        acc[6] += bf_lo(u0.w); acc[7] += bf_hi(u0.w);
        acc[0] += bf_lo(u1.x); acc[1] += bf_hi(u1.x);
        acc[2] += bf_lo(u1.y); acc[3] += bf_hi(u1.y);
        acc[4] += bf_lo(u1.z); acc[5] += bf_hi(u1.z);
        acc[6] += bf_lo(u1.w); acc[7] += bf_hi(u1.w);
    }
    if (e < end) {
        int s = col[e];
        uint4 u = G[(long)s * 16 + seg];
        acc[0] += bf_lo(u.x); acc[1] += bf_hi(u.x);
        acc[2] += bf_lo(u.y); acc[3] += bf_hi(u.y);
        acc[4] += bf_lo(u.z); acc[5] += bf_hi(u.z);
        acc[6] += bf_lo(u.w); acc[7] += bf_hi(u.w);
    }
#pragma unroll
    for (int off = 16; off < 64; off <<= 1)
#pragma unroll
        for (int j = 0; j < 8; ++j) acc[j] += __shfl_xor(acc[j], off);

    if (q == 0) {
        uint4 u = G[(long)r * 16 + seg];
        acc[0] += bf_lo(u.x); acc[1] += bf_hi(u.x);
        acc[2] += bf_lo(u.y); acc[3] += bf_hi(u.y);
        acc[4] += bf_lo(u.z); acc[5] += bf_hi(u.z);
        acc[6] += bf_lo(u.w); acc[7] += bf_hi(u.w);
        const float d = dis[r];
        float4 o0, o1;
        o0.x = fmaxf(acc[0] * d + b1[cl + 0], 0.f);
        o0.y = fmaxf(acc[1] * d + b1[cl + 1], 0.f);
        o0.z = fmaxf(acc[2] * d + b1[cl + 2], 0.f);
        o0.w = fmaxf(acc[3] * d + b1[cl + 3], 0.f);
        o1.x = fmaxf(acc[4] * d + b1[cl + 4], 0.f);
        o1.y = fmaxf(acc[5] * d + b1[cl + 5], 0.f);
        o1.z = fmaxf(acc[6] * d + b1[cl + 6], 0.f);
        o1.w = fmaxf(acc[7] * d + b1[cl + 7], 0.f);
        *(float4*)&a1[(long)r * HID + cl] = o0;
        *(float4*)&a1[(long)r * HID + cl + 4] = o1;
    }
}

// ===== layer-2 aggregate (bf16 gather, fp32 acc) =====

__global__ __launch_bounds__(256) void k_agg2(const int* __restrict__ row_ptr,
                                              const int* __restrict__ col,
                                              const float* __restrict__ dis,
                                              const unsigned short* __restrict__ g3,
                                              const float* __restrict__ b2,
                                              float* __restrict__ out) {
    int r = blockIdx.x * 4 + (threadIdx.x >> 6);
    if (r >= N_NODES) return;
    const int lane = threadIdx.x & 63;
    const int q = lane >> 3;
    const int seg = lane & 7;
    const int cl = seg << 3;
    const uint4* G = (const uint4*)g3;
    const int beg = row_ptr[r], end = row_ptr[r + 1];

    float acc[8] = {};
    int e = beg + q;
    for (; e + 8 < end; e += 16) {
        int s0 = col[e], s1 = col[e + 8];
        uint4 u0 = G[(long)s0 * 8 + seg];
        uint4 u1 = G[(long)s1 * 8 + seg];
        acc[0] += bf_lo(u0.x); acc[1] += bf_hi(u0.x);
        acc[2] += bf_lo(u0.y); acc[3] += bf_hi(u0.y);
        acc[4] += bf_lo(u0.z); acc[5] += bf_hi(u0.z);
        acc[6] += bf_lo(u0.w); acc[7] += bf_hi(u0.w);
        acc[0] += bf_lo(u1.x); acc[1] += bf_hi(u1.x);
        acc[2] += bf_lo(u1.y); acc[3] += bf_hi(u1.y);
        acc[4] += bf_lo(u1.z); acc[5] += bf_hi(u1.z);
        acc[6] += bf_lo(u1.w); acc[7] += bf_hi(u1.w);
    }
    if (e < end) {
        int s = col[e];
        uint4 u = G[(long)s * 8 + seg];
        acc[0] += bf_lo(u.x); acc[1] += bf_hi(u.x);
        acc[2] += bf_lo(u.y); acc[3] += bf_hi(u.y);
        acc[4] += bf_lo(u.z); acc[5] += bf_hi(u.z);
        acc[6] += bf_lo(u.w); acc[7] += bf_hi(u.w);
    }
#pragma unroll
    for (int off = 8; off < 64; off <<= 1)
#pragma unroll
        for (int j = 0; j < 8; ++j) acc[j] += __shfl_xor(acc[j], off);

    if (q == 0) {
        uint4 u = G[(long)r * 8 + seg];
        acc[0] += bf_lo(u.x); acc[1] += bf_hi(u.x);
        acc[2] += bf_lo(u.y); acc[3] += bf_hi(u.y);
        acc[4] += bf_lo(u.z); acc[5] += bf_hi(u.z);
        acc[6] += bf_lo(u.w); acc[7] += bf_hi(u.w);
        const float d = dis[r];
        float4 o0, o1;
        o0.x = acc[0] * d + b2[cl + 0];
        o0.y = acc[1] * d + b2[cl + 1];
        o0.z = acc[2] * d + b2[cl + 2];
        o0.w = acc[3] * d + b2[cl + 3];
        o1.x = acc[4] * d + b2[cl + 4];
        o1.y = acc[5] * d + b2[cl + 5];
        o1.z = acc[6] * d + b2[cl + 6];
        o1.w = acc[7] * d + b2[cl + 7];
        *(float4*)&out[(long)r * OUT_CH + cl] = o0;
        *(float4*)&out[(long)r * OUT_CH + cl + 4] = o1;
    }
}

// ================= launch =================

extern "C" void kernel_launch(void* const* d_in, const int* in_sizes, int n_in,
                              void* d_out, int out_size, void* d_ws, size_t ws_size,
                              hipStream_t stream) {
    const float* x   = (const float*)d_in[0];
    const int*   ei  = (const int*)d_in[1];
    const float* W1  = (const float*)d_in[2];
    const float* b1  = (const float*)d_in[3];
    const float* W2  = (const float*)d_in[4];
    const float* b2  = (const float*)d_in[5];
    float* out = (float*)d_out;

    const int* src = ei;
    const int* dst = ei + N_EDGES;

    char* p = (char*)d_ws;
    uint2* rec   = (uint2*)p;             p += (long)N_EDGES * 8;      // 6.4 MB
    int* col     = (int*)p;               p += (long)N_EDGES * 4;      // 3.2 MB
    int* row_ptr = (int*)p;               p += 50064 * 4;
    int* bcnt    = (int*)p;               p += 256 * 4;
    int* bbase   = (int*)p;               p += 256 * 4;
    int* bcur    = (int*)p;               p += 256 * 4;
    float* dis   = (float*)p;             p += 50048 * 4;
    unsigned short* g1 = (unsigned short*)p;  p += (long)N_NODES * HID * 2;
    float* a1    = (float*)p;             p += (long)N_NODES * HID * 4;
    unsigned short* g3 = (unsigned short*)p;

    const int B = 256;

    k_zero_small<<<1, B, 0, stream>>>(bcnt);
    kb_hist<<<(N_EDGES + 8191) / 8192, B, 0, stream>>>(dst, bcnt);
    kb_scan<<<1, B, 0, stream>>>(bcnt, bbase, bcur, row_ptr);
    kb_scatter<<<(N_EDGES + 4095) / 4096, B, 0, stream>>>(src, dst, bcur, rec);
    kc_csr<<<NBUCK, B, 0, stream>>>(bbase, rec, row_ptr, dis, col);

    k_gemm1<<<dim3((N_NODES + 63) / 64, 2), B, 0, stream>>>(x, W1, dis, g1);
    k_agg1<<<(N_NODES + 3) / 4, B, 0, stream>>>(row_ptr, col, dis, g1, b1, a1);
    k_gemm2<<<dim3((N_NODES + 63) / 64, 1), B, 0, stream>>>(a1, W2, dis, g3);
    k_agg2<<<(N_NODES + 3) / 4, B, 0, stream>>>(row_ptr, col, dis, g3, b2, out);
}

// Round 7
// 208.175 us; speedup vs baseline: 11.1143x; 1.1675x over previous
//
#include <hip/hip_runtime.h>

#define N_NODES 50000
#define N_EDGES 800000
#define IN_CH   128
#define HID     128
#define OUT_CH  64

#define NBUCK 196
#define BUCKW 256
#define XPAD  136      // 128 bf16 + 8 pad: breaks LDS bank conflicts for MFMA frag reads

typedef __attribute__((ext_vector_type(8))) short bf16x8;
typedef __attribute__((ext_vector_type(4))) float f32x4;
typedef unsigned short ushort_t;

__device__ __forceinline__ unsigned short f2bf(float f) {
    unsigned u = __float_as_uint(f);
    u += 0x7fffu + ((u >> 16) & 1u);      // RNE
    return (unsigned short)(u >> 16);
}
__device__ __forceinline__ unsigned pack2(float a, float b) {
    return (unsigned)f2bf(a) | ((unsigned)f2bf(b) << 16);
}
__device__ __forceinline__ float bf_lo(unsigned u) { return __uint_as_float(u << 16); }
__device__ __forceinline__ float bf_hi(unsigned u) { return __uint_as_float(u & 0xffff0000u); }

// ================= CSR build: two-level bucket sort =================

__global__ void k_zero_small(int* __restrict__ bcnt) {
    if (threadIdx.x < NBUCK) bcnt[threadIdx.x] = 0;
}

__global__ __launch_bounds__(256) void kb_hist(const int* __restrict__ dst,
                                               int* __restrict__ bcnt) {
    __shared__ int lh[NBUCK];
    for (int i = threadIdx.x; i < NBUCK; i += 256) lh[i] = 0;
    __syncthreads();
    int base = blockIdx.x * 8192;
#pragma unroll 4
    for (int k = 0; k < 32; ++k) {
        int e = base + k * 256 + threadIdx.x;
        if (e < N_EDGES) atomicAdd(&lh[dst[e] >> 8], 1);
    }
    __syncthreads();
    for (int i = threadIdx.x; i < NBUCK; i += 256)
        if (lh[i]) atomicAdd(&bcnt[i], lh[i]);
}

__global__ __launch_bounds__(256) void kb_scan(const int* __restrict__ bcnt,
                                               int* __restrict__ bbase,
                                               int* __restrict__ bcur,
                                               int* __restrict__ row_ptr) {
    __shared__ int s[256];
    int t = threadIdx.x;
    int v = (t < NBUCK) ? bcnt[t] : 0;
    s[t] = v;
    __syncthreads();
    for (int off = 1; off < 256; off <<= 1) {
        int u = (t >= off) ? s[t - off] : 0;
        __syncthreads();
        s[t] += u;
        __syncthreads();
    }
    int excl = s[t] - v;
    if (t < NBUCK) { bbase[t] = excl; bcur[t] = excl; }
    if (t == 0) { bbase[NBUCK] = N_EDGES; row_ptr[N_NODES] = N_EDGES; }
}

__global__ __launch_bounds__(256) void kb_scatter(const int* __restrict__ src,
                                                  const int* __restrict__ dst,
                                                  int* __restrict__ bcur,
                                                  uint2* __restrict__ rec) {
    __shared__ int lh[NBUCK];
    __shared__ int gbase[NBUCK];
    for (int i = threadIdx.x; i < NBUCK; i += 256) lh[i] = 0;
    __syncthreads();
    int base = blockIdx.x * 4096;
#pragma unroll 4
    for (int k = 0; k < 16; ++k) {
        int e = base + k * 256 + threadIdx.x;
        if (e < N_EDGES) atomicAdd(&lh[dst[e] >> 8], 1);
    }
    __syncthreads();
    for (int i = threadIdx.x; i < NBUCK; i += 256) {
        int c = lh[i];
        gbase[i] = c ? atomicAdd(&bcur[i], c) : 0;
    }
    __syncthreads();
    for (int i = threadIdx.x; i < NBUCK; i += 256) lh[i] = 0;
    __syncthreads();
#pragma unroll 4
    for (int k = 0; k < 16; ++k) {
        int e = base + k * 256 + threadIdx.x;
        if (e < N_EDGES) {
            int d = dst[e], b = d >> 8;
            int rk = atomicAdd(&lh[b], 1);
            rec[gbase[b] + rk] = make_uint2((unsigned)src[e], (unsigned)d);
        }
    }
}

__global__ __launch_bounds__(256) void kc_csr(const int* __restrict__ bbase,
                                              const uint2* __restrict__ rec,
                                              int* __restrict__ row_ptr,
                                              float* __restrict__ dis,
                                              int* __restrict__ col) {
    __shared__ int lh[BUCKW];
    __shared__ int cur[BUCKW];
    __shared__ int s[BUCKW];
    const int b = blockIdx.x, t = threadIdx.x;
    const int lo = bbase[b], hi = bbase[b + 1];
    lh[t] = 0;
    __syncthreads();
    for (int j = lo + t; j < hi; j += 256)
        atomicAdd(&lh[(int)rec[j].y - (b << 8)], 1);
    __syncthreads();
    int deg = lh[t];
    s[t] = deg;
    __syncthreads();
    for (int off = 1; off < 256; off <<= 1) {
        int u = (t >= off) ? s[t - off] : 0;
        __syncthreads();
        s[t] += u;
        __syncthreads();
    }
    int gp = lo + s[t] - deg;
    int node = (b << 8) + t;
    if (node < N_NODES) {
        row_ptr[node] = gp;
        dis[node] = rsqrtf((float)deg + 1.0f);
    }
    cur[t] = gp;
    __syncthreads();
    for (int j = lo + t; j < hi; j += 256) {
        uint2 r = rec[j];
        int pos = atomicAdd(&cur[(int)r.y - (b << 8)], 1);
        col[pos] = (int)r.x;
    }
}

// ========== weight prep: W1t[c][k]=bf16(W1[k][c]), W2t[c][k]=bf16(W2[k][c]) ==========

__global__ __launch_bounds__(256) void k_prep(const float* __restrict__ W1,
                                              const float* __restrict__ W2,
                                              ushort_t* __restrict__ W1t,
                                              ushort_t* __restrict__ W2t) {
    int i = blockIdx.x * 256 + threadIdx.x;
    if (i < 128 * 128) {
        int k = i >> 7, c = i & 127;
        W1t[c * 128 + k] = f2bf(W1[k * 128 + c]);
    } else {
        int j = i - 128 * 128;
        if (j < 128 * 64) {
            int k = j >> 6, c = j & 63;
            W2t[c * 128 + k] = f2bf(W2[k * 64 + c]);
        }
    }
}

// ====== MFMA GEMM1: g1 = bf16((x @ W1) * dis[row]); 64 rows x 128 cols/block ======

__global__ __launch_bounds__(256) void k_gemm1(const float* __restrict__ x,
                                               const ushort_t* __restrict__ W1t,
                                               const float* __restrict__ dis,
                                               ushort_t* __restrict__ g) {
    __shared__ ushort_t xs[64 * XPAD];    // 17.4 KB
    __shared__ ushort_t ws[128 * XPAD];   // 34.8 KB
    const int tid = threadIdx.x;
    const int row0 = blockIdx.x * 64;

    for (int i = tid; i < 64 * 32; i += 256) {
        int r = i >> 5, k4 = (i & 31) << 2;
        int gr = row0 + r;
        float4 v = make_float4(0.f, 0.f, 0.f, 0.f);
        if (gr < N_NODES) v = *(const float4*)&x[(long)gr * IN_CH + k4];
        ushort4 u;
        u.x = f2bf(v.x); u.y = f2bf(v.y); u.z = f2bf(v.z); u.w = f2bf(v.w);
        *(ushort4*)&xs[r * XPAD + k4] = u;
    }
    for (int i = tid; i < 128 * 16; i += 256) {
        int c = i >> 4, seg = i & 15;
        *(uint4*)&ws[c * XPAD + seg * 8] = *(const uint4*)&W1t[c * 128 + seg * 8];
    }
    __syncthreads();

    const int w = tid >> 6, lane = tid & 63;
    const int m = lane & 15, q = lane >> 4;
    const ushort_t* arow = &xs[(w * 16 + m) * XPAD + q * 8];
    const ushort_t* brow = &ws[m * XPAD + q * 8];

    f32x4 acc[8] = {};
#pragma unroll
    for (int k0 = 0; k0 < 128; k0 += 32) {
        bf16x8 a = *(const bf16x8*)(arow + k0);
#pragma unroll
        for (int nt = 0; nt < 8; ++nt) {
            bf16x8 b = *(const bf16x8*)(brow + nt * 16 * XPAD + k0);
            acc[nt] = __builtin_amdgcn_mfma_f32_16x16x32_bf16(a, b, acc[nt], 0, 0, 0);
        }
    }

#pragma unroll
    for (int reg = 0; reg < 4; ++reg) {
        int gr = row0 + w * 16 + q * 4 + reg;
        if (gr < N_NODES) {
            float d = dis[gr];
#pragma unroll
            for (int nt = 0; nt < 8; ++nt)
                g[(long)gr * HID + nt * 16 + m] = f2bf(acc[nt][reg] * d);
        }
    }
}

// ====== MFMA GEMM2: g3 = bf16((a1 @ W2) * dis[row]); 64 rows x 64 cols/block ======

__global__ __launch_bounds__(256) void k_gemm2(const ushort_t* __restrict__ a1,
                                               const ushort_t* __restrict__ W2t,
                                               const float* __restrict__ dis,
                                               ushort_t* __restrict__ g) {
    __shared__ ushort_t xs[64 * XPAD];
    __shared__ ushort_t ws[64 * XPAD];
    const int tid = threadIdx.x;
    const int row0 = blockIdx.x * 64;

    for (int i = tid; i < 64 * 16; i += 256) {
        int r = i >> 4, seg = i & 15;
        int gr = row0 + r;
        uint4 v = make_uint4(0u, 0u, 0u, 0u);
        if (gr < N_NODES) v = *(const uint4*)&a1[(long)gr * HID + seg * 8];
        *(uint4*)&xs[r * XPAD + seg * 8] = v;
    }
    for (int i = tid; i < 64 * 16; i += 256) {
        int c = i >> 4, seg = i & 15;
        *(uint4*)&ws[c * XPAD + seg * 8] = *(const uint4*)&W2t[c * 128 + seg * 8];
    }
    __syncthreads();

    const int w = tid >> 6, lane = tid & 63;
    const int m = lane & 15, q = lane >> 4;
    const ushort_t* arow = &xs[(w * 16 + m) * XPAD + q * 8];
    const ushort_t* brow = &ws[m * XPAD + q * 8];

    f32x4 acc[4] = {};
#pragma unroll
    for (int k0 = 0; k0 < 128; k0 += 32) {
        bf16x8 a = *(const bf16x8*)(arow + k0);
#pragma unroll
        for (int nt = 0; nt < 4; ++nt) {
            bf16x8 b = *(const bf16x8*)(brow + nt * 16 * XPAD + k0);
            acc[nt] = __builtin_amdgcn_mfma_f32_16x16x32_bf16(a, b, acc[nt], 0, 0, 0);
        }
    }

#pragma unroll
    for (int reg = 0; reg < 4; ++reg) {
        int gr = row0 + w * 16 + q * 4 + reg;
        if (gr < N_NODES) {
            float d = dis[gr];
#pragma unroll
            for (int nt = 0; nt < 4; ++nt)
                g[(long)gr * OUT_CH + nt * 16 + m] = f2bf(acc[nt][reg] * d);
        }
    }
}

// ===== layer-1 aggregate (bf16 gather, fp32 acc) -> bf16 a1 with relu+bias =====

__global__ __launch_bounds__(256) void k_agg1(const int* __restrict__ row_ptr,
                                              const int* __restrict__ col,
                                              const float* __restrict__ dis,
                                              const ushort_t* __restrict__ g1,
                                              const float* __restrict__ b1,
                                              ushort_t* __restrict__ a1) {
    int r = blockIdx.x * 4 + (threadIdx.x >> 6);
    if (r >= N_NODES) return;
    const int lane = threadIdx.x & 63;
    const int q = lane >> 4;
    const int seg = lane & 15;
    const int cl = seg << 3;
    const uint4* G = (const uint4*)g1;
    const int beg = row_ptr[r], end = row_ptr[r + 1];

    float acc[8] = {};
    int e = beg + q;
    for (; e + 4 < end; e += 8) {
        int s0 = col[e], s1 = col[e + 4];
        uint4 u0 = G[(long)s0 * 16 + seg];
        uint4 u1 = G[(long)s1 * 16 + seg];
        acc[0] += bf_lo(u0.x); acc[1] += bf_hi(u0.x);
        acc[2] += bf_lo(u0.y); acc[3] += bf_hi(u0.y);
        acc[4] += bf_lo(u0.z); acc[5] += bf_hi(u0.z);
        acc[6] += bf_lo(u0.w); acc[7] += bf_hi(u0.w);
        acc[0] += bf_lo(u1.x); acc[1] += bf_hi(u1.x);
        acc[2] += bf_lo(u1.y); acc[3] += bf_hi(u1.y);
        acc[4] += bf_lo(u1.z); acc[5] += bf_hi(u1.z);
        acc[6] += bf_lo(u1.w); acc[7] += bf_hi(u1.w);
    }
    if (e < end) {
        int s = col[e];
        uint4 u = G[(long)s * 16 + seg];
        acc[0] += bf_lo(u.x); acc[1] += bf_hi(u.x);
        acc[2] += bf_lo(u.y); acc[3] += bf_hi(u.y);
        acc[4] += bf_lo(u.z); acc[5] += bf_hi(u.z);
        acc[6] += bf_lo(u.w); acc[7] += bf_hi(u.w);
    }
#pragma unroll
    for (int off = 16; off < 64; off <<= 1)
#pragma unroll
        for (int j = 0; j < 8; ++j) acc[j] += __shfl_xor(acc[j], off);

    if (q == 0) {
        uint4 u = G[(long)r * 16 + seg];
        acc[0] += bf_lo(u.x); acc[1] += bf_hi(u.x);
        acc[2] += bf_lo(u.y); acc[3] += bf_hi(u.y);
        acc[4] += bf_lo(u.z); acc[5] += bf_hi(u.z);
        acc[6] += bf_lo(u.w); acc[7] += bf_hi(u.w);
        const float d = dis[r];
        float o[8];
#pragma unroll
        for (int j = 0; j < 8; ++j) o[j] = fmaxf(acc[j] * d + b1[cl + j], 0.f);
        uint4 pw;
        pw.x = pack2(o[0], o[1]); pw.y = pack2(o[2], o[3]);
        pw.z = pack2(o[4], o[5]); pw.w = pack2(o[6], o[7]);
        *(uint4*)&a1[(long)r * HID + cl] = pw;
    }
}

// ===== layer-2 aggregate (bf16 gather, fp32 acc) -> fp32 out =====

__global__ __launch_bounds__(256) void k_agg2(const int* __restrict__ row_ptr,
                                              const int* __restrict__ col,
                                              const float* __restrict__ dis,
                                              const ushort_t* __restrict__ g3,
                                              const float* __restrict__ b2,
                                              float* __restrict__ out) {
    int r = blockIdx.x * 4 + (threadIdx.x >> 6);
    if (r >= N_NODES) return;
    const int lane = threadIdx.x & 63;
    const int q = lane >> 3;
    const int seg = lane & 7;
    const int cl = seg << 3;
    const uint4* G = (const uint4*)g3;
    const int beg = row_ptr[r], end = row_ptr[r + 1];

    float acc[8] = {};
    int e = beg + q;
    for (; e + 8 < end; e += 16) {
        int s0 = col[e], s1 = col[e + 8];
        uint4 u0 = G[(long)s0 * 8 + seg];
        uint4 u1 = G[(long)s1 * 8 + seg];
        acc[0] += bf_lo(u0.x); acc[1] += bf_hi(u0.x);
        acc[2] += bf_lo(u0.y); acc[3] += bf_hi(u0.y);
        acc[4] += bf_lo(u0.z); acc[5] += bf_hi(u0.z);
        acc[6] += bf_lo(u0.w); acc[7] += bf_hi(u0.w);
        acc[0] += bf_lo(u1.x); acc[1] += bf_hi(u1.x);
        acc[2] += bf_lo(u1.y); acc[3] += bf_hi(u1.y);
        acc[4] += bf_lo(u1.z); acc[5] += bf_hi(u1.z);
        acc[6] += bf_lo(u1.w); acc[7] += bf_hi(u1.w);
    }
    if (e < end) {
        int s = col[e];
        uint4 u = G[(long)s * 8 + seg];
        acc[0] += bf_lo(u.x); acc[1] += bf_hi(u.x);
        acc[2] += bf_lo(u.y); acc[3] += bf_hi(u.y);
        acc[4] += bf_lo(u.z); acc[5] += bf_hi(u.z);
        acc[6] += bf_lo(u.w); acc[7] += bf_hi(u.w);
    }
#pragma unroll
    for (int off = 8; off < 64; off <<= 1)
#pragma unroll
        for (int j = 0; j < 8; ++j) acc[j] += __shfl_xor(acc[j], off);

    if (q == 0) {
        uint4 u = G[(long)r * 8 + seg];
        acc[0] += bf_lo(u.x); acc[1] += bf_hi(u.x);
        acc[2] += bf_lo(u.y); acc[3] += bf_hi(u.y);
        acc[4] += bf_lo(u.z); acc[5] += bf_hi(u.z);
        acc[6] += bf_lo(u.w); acc[7] += bf_hi(u.w);
        const float d = dis[r];
        float4 o0, o1;
        o0.x = acc[0] * d + b2[cl + 0];
        o0.y = acc[1] * d + b2[cl + 1];
        o0.z = acc[2] * d + b2[cl + 2];
        o0.w = acc[3] * d + b2[cl + 3];
        o1.x = acc[4] * d + b2[cl + 4];
        o1.y = acc[5] * d + b2[cl + 5];
        o1.z = acc[6] * d + b2[cl + 6];
        o1.w = acc[7] * d + b2[cl + 7];
        *(float4*)&out[(long)r * OUT_CH + cl] = o0;
        *(float4*)&out[(long)r * OUT_CH + cl + 4] = o1;
    }
}

// ================= launch =================

extern "C" void kernel_launch(void* const* d_in, const int* in_sizes, int n_in,
                              void* d_out, int out_size, void* d_ws, size_t ws_size,
                              hipStream_t stream) {
    const float* x   = (const float*)d_in[0];
    const int*   ei  = (const int*)d_in[1];
    const float* W1  = (const float*)d_in[2];
    const float* b1  = (const float*)d_in[3];
    const float* W2  = (const float*)d_in[4];
    const float* b2  = (const float*)d_in[5];
    float* out = (float*)d_out;

    const int* src = ei;
    const int* dst = ei + N_EDGES;

    char* p = (char*)d_ws;
    uint2* rec   = (uint2*)p;             p += (long)N_EDGES * 8;
    int* col     = (int*)p;               p += (long)N_EDGES * 4;
    int* row_ptr = (int*)p;               p += 50064 * 4;
    int* bcnt    = (int*)p;               p += 256 * 4;
    int* bbase   = (int*)p;               p += 256 * 4;
    int* bcur    = (int*)p;               p += 256 * 4;
    float* dis   = (float*)p;             p += 50048 * 4;
    ushort_t* W1t = (ushort_t*)p;         p += 128 * 128 * 2;
    ushort_t* W2t = (ushort_t*)p;         p += 128 * 64 * 2;
    ushort_t* g1  = (ushort_t*)p;         p += (long)N_NODES * HID * 2;
    ushort_t* a1  = (ushort_t*)p;         p += (long)N_NODES * HID * 2;
    ushort_t* g3  = (ushort_t*)p;

    const int B = 256;

    k_zero_small<<<1, B, 0, stream>>>(bcnt);
    k_prep<<<96, B, 0, stream>>>(W1, W2, W1t, W2t);
    kb_hist<<<(N_EDGES + 8191) / 8192, B, 0, stream>>>(dst, bcnt);
    kb_scan<<<1, B, 0, stream>>>(bcnt, bbase, bcur, row_ptr);
    kb_scatter<<<(N_EDGES + 4095) / 4096, B, 0, stream>>>(src, dst, bcur, rec);
    kc_csr<<<NBUCK, B, 0, stream>>>(bbase, rec, row_ptr, dis, col);

    k_gemm1<<<(N_NODES + 63) / 64, B, 0, stream>>>(x, W1t, dis, g1);
    k_agg1<<<(N_NODES + 3) / 4, B, 0, stream>>>(row_ptr, col, dis, g1, b1, a1);
    k_gemm2<<<(N_NODES + 63) / 64, B, 0, stream>>>(a1, W2t, dis, g3);
    k_agg2<<<(N_NODES + 3) / 4, B, 0, stream>>>(row_ptr, col, dis, g3, b2, out);
}